// Round 3
// baseline (1769.145 us; speedup 1.0000x reference)
//
#include <hip/hip_runtime.h>
#include <hip/hip_bf16.h>

// ShockPropagationGNN — round 2.
// Theory: inputs are bf16 (harness policy), OUTPUT IS FP32 (reference dtype).
// fp32 internal compute; xh stored bf16. Input dtype auto-detected on device.
// Sentinels: out=4.0 if in_sizes mismatch, out=8.0 if ws_size too small.

#define N_NODES 50000
#define N_EDGES 200000
#define ETOT    (N_EDGES + N_NODES)   // edges + self loops
#define HID     128
#define LN_EPS  1e-5f
#define NEG     0.2f

typedef __hip_bfloat16 bf16;

// legacy symbol, in case the harness expects it
__global__ void ShockPropagationGNN_56899726737514_kernel() {}

// flag-adaptive param read: bf16 or fp32 storage
__device__ __forceinline__ float pread(const void* p, size_t i, int isbf) {
    if (isbf) {
        unsigned int u = ((const unsigned short*)p)[i];
        return __uint_as_float(u << 16);
    }
    return ((const float*)p)[i];
}

__global__ void k_fill(float* out, int n, float v) {
    int i = blockIdx.x * blockDim.x + threadIdx.x;
    if (i < n) out[i] = v;
}

// ---------------------------------------------------------------- dtype detect
// Read x-buffer as u16. True bf16 ~N(0,1): every u16 has exponent ~127+-31.
// fp32 storage: even u16 slots are low mantissa halves -> random exponents.
__global__ void k_detect(const unsigned short* __restrict__ xbuf,
                         int* __restrict__ flag) {
    int sane = 0;
    for (int j = threadIdx.x; j < 4096; j += 64) {
        unsigned short v = xbuf[2 * j];
        int e = (v >> 7) & 0xFF;
        if (v == 0 || (e > 96 && e < 160)) sane++;
    }
    for (int off = 32; off > 0; off >>= 1) sane += __shfl_down(sane, off);
    if (threadIdx.x == 0) flag[0] = (sane * 10 >= 4096 * 9) ? 1 : 0;  // 1 = bf16
}

__global__ void k_convert(const void* __restrict__ src, float* __restrict__ dst,
                          int n, const int* __restrict__ flag) {
    int i = blockIdx.x * blockDim.x + threadIdx.x;
    if (i < n) dst[i] = pread(src, i, flag[0]);
}

// ---------------------------------------------------------------- utilities
__global__ void k_zero(float* down, int* deg, int* fill) {
    int i = blockIdx.x * blockDim.x + threadIdx.x;
    if (i < N_NODES) { down[i] = 0.f; deg[i] = 0; fill[i] = 0; }
}

__global__ void k_down(const int* __restrict__ ei, const int* __restrict__ shock,
                       float* __restrict__ down) {
    int e = blockIdx.x * blockDim.x + threadIdx.x;
    if (e < N_EDGES) {
        if (shock[ei[e]] != 0) down[ei[N_EDGES + e]] = 1.f;
    }
}

__global__ void k_hist(const int* __restrict__ ei, int* __restrict__ deg) {
    int e = blockIdx.x * blockDim.x + threadIdx.x;
    if (e < ETOT) {
        int d = (e < N_EDGES) ? ei[N_EDGES + e] : (e - N_EDGES);
        atomicAdd(&deg[d], 1);
    }
}

// single-block scan, shfl-based
__global__ void k_scan(const int* __restrict__ deg, int* __restrict__ row_start) {
    __shared__ int wsum[16];
    __shared__ int wexcl[16];
    __shared__ int tot_s;
    __shared__ int carry_s;
    int tid = threadIdx.x, lane = tid & 63, wid = tid >> 6;
    if (tid == 0) carry_s = 0;
    __syncthreads();
    for (int base = 0; base < N_NODES; base += 1024) {
        int i = base + tid;
        int v = (i < N_NODES) ? deg[i] : 0;
        int inc = v;
#pragma unroll
        for (int off = 1; off < 64; off <<= 1) {
            int t = __shfl_up(inc, off);
            if (lane >= off) inc += t;
        }
        if (lane == 63) wsum[wid] = inc;
        __syncthreads();
        if (wid == 0) {
            int wv = (lane < 16) ? wsum[lane] : 0;
            int winc = wv;
#pragma unroll
            for (int off = 1; off < 16; off <<= 1) {
                int t = __shfl_up(winc, off);
                if (lane >= off) winc += t;
            }
            if (lane < 16) wexcl[lane] = winc - wv;
            if (lane == 15) tot_s = winc;
        }
        __syncthreads();
        int carry = carry_s;
        if (i < N_NODES) row_start[i] = carry + wexcl[wid] + (inc - v);
        __syncthreads();
        if (tid == 0) carry_s = carry + tot_s;
        __syncthreads();
    }
    if (threadIdx.x == 0) row_start[N_NODES] = ETOT;
}

__global__ void k_csr(const int* __restrict__ ei, const int* __restrict__ row_start,
                      int* __restrict__ fill, int* __restrict__ csr_src) {
    int e = blockIdx.x * blockDim.x + threadIdx.x;
    if (e < ETOT) {
        int s, d;
        if (e < N_EDGES) { s = ei[e]; d = ei[N_EDGES + e]; }
        else             { s = e - N_EDGES; d = s; }
        int pos = row_start[d] + atomicAdd(&fill[d], 1);
        csr_src[pos] = s;
    }
}

// ---------------------------------------------------------------- encoder
__global__ __launch_bounds__(128) void k_encoder(
        const void* __restrict__ xraw, const int* __restrict__ flag,
        const int* __restrict__ shock, const float* __restrict__ down,
        const float* __restrict__ enc_w, const float* __restrict__ enc_b,
        const float* __restrict__ ln_g, const float* __restrict__ ln_b,
        float* __restrict__ h) {
    int n = blockIdx.x, c = threadIdx.x;
    __shared__ float xa[18];
    __shared__ float red[4];
    int bf = flag[0];
    if (c < 16)       xa[c]  = pread(xraw, (size_t)n * 16 + c, bf);
    else if (c == 16) xa[16] = (float)shock[n];
    else if (c == 17) xa[17] = down[n];
    __syncthreads();
    float acc = enc_b[c];
#pragma unroll
    for (int k = 0; k < 18; k++) acc = fmaf(xa[k], enc_w[k * HID + c], acc);
    float s = acc, q = acc * acc;
    for (int off = 32; off > 0; off >>= 1) {
        s += __shfl_down(s, off);
        q += __shfl_down(q, off);
    }
    if ((c & 63) == 0) { red[(c >> 6) * 2] = s; red[(c >> 6) * 2 + 1] = q; }
    __syncthreads();
    float S = red[0] + red[2], Q = red[1] + red[3];
    float mu = S * (1.f / 128.f);
    float var = Q * (1.f / 128.f) - mu * mu;
    float rstd = rsqrtf(var + LN_EPS);
    float v = (acc - mu) * rstd * ln_g[c] + ln_b[c];
    h[(size_t)n * HID + c] = fmaxf(v, 0.f);
}

// ---------------------------------------------------------------- GAT GEMM
// C[50000,512](bf16) = A[50000,128](f32) @ W[128,512](f32).
#define GS 68
__global__ __launch_bounds__(256) void k_gemm(
        const float* __restrict__ A, const float* __restrict__ W,
        bf16* __restrict__ C) {
    __shared__ float As[64 * GS];   // As[k][m]
    __shared__ float Bs[64 * GS];   // Bs[k][n]
    int m0 = blockIdx.x * 64, n0 = blockIdx.y * 64;
    int t = threadIdx.x;
    int tx = t & 15, ty = t >> 4;
    float acc[4][4] = {};
    for (int kc = 0; kc < 128; kc += 64) {
        for (int idx = t; idx < 4096; idx += 256) {
            int m = idx >> 6, k = idx & 63;
            As[k * GS + m] = (m0 + m < N_NODES)
                ? A[(size_t)(m0 + m) * 128 + kc + k] : 0.f;
        }
        for (int idx = t; idx < 4096; idx += 256) {
            int k = idx >> 6, n = idx & 63;
            Bs[k * GS + n] = W[(size_t)(kc + k) * 512 + n0 + n];
        }
        __syncthreads();
#pragma unroll 4
        for (int k = 0; k < 64; k++) {
            float4 a4 = *(const float4*)&As[k * GS + ty * 4];
            float4 b4 = *(const float4*)&Bs[k * GS + tx * 4];
            float av[4] = {a4.x, a4.y, a4.z, a4.w};
            float bv[4] = {b4.x, b4.y, b4.z, b4.w};
#pragma unroll
            for (int i = 0; i < 4; i++)
#pragma unroll
                for (int j = 0; j < 4; j++)
                    acc[i][j] = fmaf(av[i], bv[j], acc[i][j]);
        }
        __syncthreads();
    }
#pragma unroll
    for (int i = 0; i < 4; i++) {
        int m = m0 + ty * 4 + i;
        if (m < N_NODES) {
            size_t o = (size_t)m * 512 + n0 + tx * 4;
#pragma unroll
            for (int j = 0; j < 4; j++)
                C[o + j] = __float2bfloat16(acc[i][j]);
        }
    }
}

// ---------------------------------------------------------------- attention logits
__global__ __launch_bounds__(256) void k_logits(
        const bf16* __restrict__ xh, const float* __restrict__ asrc,
        const float* __restrict__ adst,
        float* __restrict__ al_src, float* __restrict__ al_dst) {
    int n = blockIdx.x;
    int w = threadIdx.x >> 6;   // head
    int l = threadIdx.x & 63;
    const bf16* row = xh + (size_t)n * 512 + w * 128;
    const float* ps = asrc + w * 128;
    const float* pd = adst + w * 128;
    float r0 = __bfloat162float(row[l]), r1 = __bfloat162float(row[l + 64]);
    float s1 = r0 * ps[l] + r1 * ps[l + 64];
    float s2 = r0 * pd[l] + r1 * pd[l + 64];
    for (int off = 32; off > 0; off >>= 1) {
        s1 += __shfl_down(s1, off);
        s2 += __shfl_down(s2, off);
    }
    if (l == 0) { al_src[n * 4 + w] = s1; al_dst[n * 4 + w] = s2; }
}

// ---------------------------------------------------------------- aggregation
__global__ __launch_bounds__(128) void k_aggregate(
        const bf16* __restrict__ xh, const float* __restrict__ al_src,
        const float* __restrict__ al_dst,
        const int* __restrict__ row_start, const int* __restrict__ csr_src,
        const float* __restrict__ bias,
        const float* __restrict__ bn_g, const float* __restrict__ bn_b,
        const float* __restrict__ bn_m, const float* __restrict__ bn_v,
        float* __restrict__ h, int relu_flag) {
    int n = blockIdx.x, c = threadIdx.x;
    int r0 = row_start[n], r1 = row_start[n + 1];
    float ad[4];
#pragma unroll
    for (int hh = 0; hh < 4; hh++) ad[hh] = al_dst[n * 4 + hh];
    float mh[4] = {-1e30f, -1e30f, -1e30f, -1e30f};
    for (int j = r0; j < r1; j++) {
        int s = csr_src[j];
#pragma unroll
        for (int hh = 0; hh < 4; hh++) {
            float a = al_src[s * 4 + hh] + ad[hh];
            a = (a >= 0.f) ? a : NEG * a;
            mh[hh] = fmaxf(mh[hh], a);
        }
    }
    float sh[4] = {0.f, 0.f, 0.f, 0.f};
    float acc[4] = {0.f, 0.f, 0.f, 0.f};
    for (int j = r0; j < r1; j++) {
        int s = csr_src[j];
        const bf16* row = xh + (size_t)s * 512 + c;
#pragma unroll
        for (int hh = 0; hh < 4; hh++) {
            float a = al_src[s * 4 + hh] + ad[hh];
            a = (a >= 0.f) ? a : NEG * a;
            float w = __expf(a - mh[hh]);
            sh[hh] += w;
            acc[hh] += w * __bfloat162float(row[hh * 128]);
        }
    }
    float v = 0.f;
#pragma unroll
    for (int hh = 0; hh < 4; hh++) v += acc[hh] / (sh[hh] + 1e-16f);
    v = 0.25f * v + bias[c];
    v = (v - bn_m[c]) * rsqrtf(bn_v[c] + LN_EPS) * bn_g[c] + bn_b[c];
    if (relu_flag) v = fmaxf(v, 0.f);
    h[(size_t)n * HID + c] = v;
}

// ---------------------------------------------------------------- edge MLP
__global__ __launch_bounds__(256) void k_edgemlp(
        const float* __restrict__ h, const int* __restrict__ ei,
        const void* __restrict__ eraw, const int* __restrict__ flag,
        const float* __restrict__ em1_w, const float* __restrict__ em1_b,
        const float* __restrict__ lng, const float* __restrict__ lnb,
        const float* __restrict__ em2_w, const float* __restrict__ em2_b,
        const float* __restrict__ em3_w, const float* __restrict__ em3_b,
        float* __restrict__ out) {
    __shared__ float in_s[8][264];
    __shared__ float z_s[8][132];
    __shared__ float stats[8][2];
    int t = threadIdx.x;
    int e0 = blockIdx.x * 8;
    int bf = flag[0];
    for (int idx = t; idx < 8 * 264; idx += 256) {
        int el = idx / 264, k = idx - el * 264;
        int e = e0 + el;
        float v;
        if (k < 128)      v = h[(size_t)ei[e] * 128 + k];
        else if (k < 256) v = h[(size_t)ei[N_EDGES + e] * 128 + (k - 128)];
        else              v = pread(eraw, (size_t)e * 8 + (k - 256), bf);
        in_s[el][k] = v;
    }
    __syncthreads();
    // layer 1: tx = channel quad (32), ty = edge (8)
    int tx = t & 31, ty = t >> 5;
    float acc[4];
#pragma unroll
    for (int j = 0; j < 4; j++) acc[j] = em1_b[tx * 4 + j];
    for (int k = 0; k < 264; k++) {
        float in = in_s[ty][k];
        float4 w4 = *(const float4*)(em1_w + (size_t)k * 128 + tx * 4);
        acc[0] = fmaf(in, w4.x, acc[0]);
        acc[1] = fmaf(in, w4.y, acc[1]);
        acc[2] = fmaf(in, w4.z, acc[2]);
        acc[3] = fmaf(in, w4.w, acc[3]);
    }
    float s = acc[0] + acc[1] + acc[2] + acc[3];
    float q = acc[0] * acc[0] + acc[1] * acc[1] + acc[2] * acc[2] + acc[3] * acc[3];
    for (int off = 16; off > 0; off >>= 1) {
        s += __shfl_down(s, off, 32);
        q += __shfl_down(q, off, 32);
    }
    if (tx == 0) { stats[ty][0] = s; stats[ty][1] = q; }
    __syncthreads();
    float mu = stats[ty][0] * (1.f / 128.f);
    float var = stats[ty][1] * (1.f / 128.f) - mu * mu;
    float rstd = rsqrtf(var + LN_EPS);
#pragma unroll
    for (int j = 0; j < 4; j++) {
        int cc = tx * 4 + j;
        float z = (acc[j] - mu) * rstd * lng[cc] + lnb[cc];
        z_s[ty][cc] = fmaxf(z, 0.f);
    }
    __syncthreads();
    // layer 2 + 3: wave g handles edges {g, g+4}; lane d = hidden channel
    int d = t & 63, g = t >> 6;
    float a0 = em2_b[d], a1 = a0;
    for (int k = 0; k < 128; k++) {
        float w = em2_w[(size_t)k * 64 + d];
        a0 = fmaf(z_s[g][k], w, a0);
        a1 = fmaf(z_s[g + 4][k], w, a1);
    }
    float w3 = em3_w[d];
    float p0 = fmaxf(a0, 0.f) * w3;
    float p1 = fmaxf(a1, 0.f) * w3;
    for (int off = 32; off > 0; off >>= 1) {
        p0 += __shfl_down(p0, off);
        p1 += __shfl_down(p1, off);
    }
    if (d == 0) {
        float b3 = em3_b[0];
        out[e0 + g]     = p0 + b3;
        out[e0 + g + 4] = p1 + b3;
    }
}

// ---------------------------------------------------------------- launch
extern "C" __attribute__((visibility("default")))
void kernel_launch(void* const* d_in, const int* in_sizes, int n_in,
                   void* d_out, int out_size, void* d_ws, size_t ws_size,
                   hipStream_t stream) {
    float* out = (float*)d_out;   // reference output dtype: fp32

    // --- sentinel: input size map mismatch -> fill 4.0
    static const int EXP_SIZES[24] = {
        800000, 400000, 1600000, 50000, 2304, 128, 128, 128,
        196608, 1536, 1536, 384, 384, 384, 384, 384,
        33792, 128, 128, 128, 8192, 64, 64, 1};
    bool ok = (n_in == 24) && (out_size == N_EDGES);
    if (ok) for (int i = 0; i < 24; i++) ok = ok && (in_sizes[i] == EXP_SIZES[i]);
    if (!ok) {
        k_fill<<<(out_size + 255) / 256, 256, 0, stream>>>(out, out_size, 4.0f);
        return;
    }
    // --- sentinel: workspace too small -> fill 8.0
    if (ws_size < (size_t)81200000) {
        k_fill<<<(out_size + 255) / 256, 256, 0, stream>>>(out, out_size, 8.0f);
        return;
    }

    const int* ei    = (const int*)d_in[1];
    const int* shock = (const int*)d_in[3];

    char* ws = (char*)d_ws;
    float* h       = (float*)(ws + 0);            // 25,600,000 B
    bf16*  xh      = (bf16*) (ws + 25600000);     // 51,200,000 B
    float* al_s    = (float*)(ws + 76800000);     // 800,000
    float* al_d    = (float*)(ws + 77600000);     // 800,000
    float* down    = (float*)(ws + 78400000);     // 200,000
    int*   deg     = (int*)  (ws + 78600000);     // 200,000
    int*   row_st  = (int*)  (ws + 78800000);     // 200,064 (padded)
    int*   fill    = (int*)  (ws + 79000064);     // 200,000
    int*   csr_src = (int*)  (ws + 79200064);     // 1,000,000
    int*   flag    = (int*)  (ws + 80200064);     // 64
    float* pool    = (float*)(ws + 80200128);     // ~987 KB weight conversions

    float* cencw  = pool;                 // 2304
    float* cencb  = cencw  + 2304;        // 128
    float* cenlg  = cencb  + 128;         // 128
    float* cenlb  = cenlg  + 128;         // 128
    float* cgatw  = cenlb  + 128;         // 196608
    float* casrc  = cgatw  + 196608;      // 1536
    float* cadst  = casrc  + 1536;        // 1536
    float* cbias  = cadst  + 1536;        // 384
    float* cbng   = cbias  + 384;         // 384
    float* cbnb   = cbng   + 384;         // 384
    float* cbnm   = cbnb   + 384;         // 384
    float* cbnv   = cbnm   + 384;         // 384
    float* cem1w  = cbnv   + 384;         // 33792
    float* cem1b  = cem1w  + 33792;       // 128
    float* cemlg  = cem1b  + 128;         // 128
    float* cemlb  = cemlg  + 128;         // 128
    float* cem2w  = cemlb  + 128;         // 8192
    float* cem2b  = cem2w  + 8192;        // 64
    float* cem3w  = cem2b  + 64;          // 64
    float* cem3b  = cem3w  + 64;          // 1

    k_detect<<<1, 64, 0, stream>>>((const unsigned short*)d_in[0], flag);

    struct Conv { int idx; float* dst; int n; };
    const Conv convs[] = {
        {4,  cencw, 2304},   {5,  cencb, 128},
        {6,  cenlg, 128},    {7,  cenlb, 128},
        {8,  cgatw, 196608}, {9,  casrc, 1536},
        {10, cadst, 1536},   {11, cbias, 384},
        {12, cbng,  384},    {13, cbnb,  384},
        {14, cbnm,  384},    {15, cbnv,  384},
        {16, cem1w, 33792},  {17, cem1b, 128},
        {18, cemlg, 128},    {19, cemlb, 128},
        {20, cem2w, 8192},   {21, cem2b, 64},
        {22, cem3w, 64},     {23, cem3b, 1},
    };
    for (const Conv& cv : convs)
        k_convert<<<(cv.n + 255) / 256, 256, 0, stream>>>(d_in[cv.idx], cv.dst, cv.n, flag);

    k_zero<<<(N_NODES + 255) / 256, 256, 0, stream>>>(down, deg, fill);
    k_down<<<(N_EDGES + 255) / 256, 256, 0, stream>>>(ei, shock, down);
    k_hist<<<(ETOT + 255) / 256, 256, 0, stream>>>(ei, deg);
    k_scan<<<1, 1024, 0, stream>>>(deg, row_st);
    k_csr<<<(ETOT + 255) / 256, 256, 0, stream>>>(ei, row_st, fill, csr_src);
    k_encoder<<<N_NODES, 128, 0, stream>>>(d_in[0], flag, shock, down,
                                           cencw, cencb, cenlg, cenlb, h);
    for (int i = 0; i < 3; i++) {
        k_gemm<<<dim3((N_NODES + 63) / 64, 8), 256, 0, stream>>>(
            h, cgatw + (size_t)i * 128 * 512, xh);
        k_logits<<<N_NODES, 256, 0, stream>>>(
            xh, casrc + i * 512, cadst + i * 512, al_s, al_d);
        k_aggregate<<<N_NODES, 128, 0, stream>>>(
            xh, al_s, al_d, row_st, csr_src,
            cbias + i * 128, cbng + i * 128, cbnb + i * 128,
            cbnm + i * 128, cbnv + i * 128, h, (i < 2) ? 1 : 0);
    }
    k_edgemlp<<<N_EDGES / 8, 256, 0, stream>>>(
        h, ei, d_in[2], flag, cem1w, cem1b, cemlg, cemlb,
        cem2w, cem2b, cem3w, cem3b, out);
}

// Round 4
// 685.483 us; speedup vs baseline: 2.5809x; 2.5809x over previous
//
#include <hip/hip_runtime.h>
#include <hip/hip_bf16.h>

// ShockPropagationGNN — round 3: MFMA for GAT GEMMs + edge MLP.
// Inputs bf16 (auto-detected), output fp32. h stored bf16 (feeds MFMA).

#define N_NODES 50000
#define N_EDGES 200000
#define ETOT    (N_EDGES + N_NODES)
#define HID     128
#define LN_EPS  1e-5f
#define NEG     0.2f

typedef __hip_bfloat16 bf16;
typedef __attribute__((ext_vector_type(8))) short v8s;
typedef __attribute__((ext_vector_type(4))) float v4f;
#define MFMA(a, b, c) __builtin_amdgcn_mfma_f32_16x16x32_bf16(a, b, c, 0, 0, 0)

__device__ __forceinline__ float b2f(unsigned short s) {
    return __uint_as_float(((unsigned int)s) << 16);
}
__device__ __forceinline__ unsigned short f2b(float f) {
    __hip_bfloat16 h = __float2bfloat16(f);
    return *reinterpret_cast<unsigned short*>(&h);
}
__device__ __forceinline__ float pread(const void* p, size_t i, int isbf) {
    if (isbf) return b2f(((const unsigned short*)p)[i]);
    return ((const float*)p)[i];
}

__global__ void k_fill(float* out, int n, float v) {
    int i = blockIdx.x * blockDim.x + threadIdx.x;
    if (i < n) out[i] = v;
}

// ------------------------------------------------------------ dtype detect
__global__ void k_detect(const unsigned short* __restrict__ xbuf,
                         int* __restrict__ flag) {
    int sane = 0;
    for (int j = threadIdx.x; j < 4096; j += 64) {
        unsigned short v = xbuf[2 * j];
        int e = (v >> 7) & 0xFF;
        if (v == 0 || (e > 96 && e < 160)) sane++;
    }
    for (int off = 32; off > 0; off >>= 1) sane += __shfl_down(sane, off);
    if (threadIdx.x == 0) flag[0] = (sane * 10 >= 4096 * 9) ? 1 : 0;
}

// ------------------------------------------------------------ prep (fused)
// zeros + all weight conversions/transposes in ONE launch.
struct PrepArgs {
    const void *encw, *encb, *enlg, *enlb, *gatw, *asrc, *adst, *bias,
               *bng, *bnb, *bnm, *bnv, *em1w, *em1b, *emlg, *emlb,
               *em2w, *em2b, *em3w, *em3b;
};
#define PREP_ITEMS (150000 + 8193 + 196608 + 36864 + 8192)
__global__ void k_prep(PrepArgs a, float* __restrict__ pool,
                       unsigned short* __restrict__ gwt,
                       unsigned short* __restrict__ w1t,
                       unsigned short* __restrict__ w2t,
                       float* __restrict__ down, int* __restrict__ deg,
                       int* __restrict__ fill, const int* __restrict__ flag) {
    int i = blockIdx.x * 256 + threadIdx.x;
    int bf = flag[0];
    if (i < 150000) {
        int which = i / 50000, idx = i - which * 50000;
        if (which == 0) down[idx] = 0.f;
        else if (which == 1) deg[idx] = 0;
        else fill[idx] = 0;
        return;
    }
    i -= 150000;
    if (i < 8193) {   // small fp32 conversions; pool layout == cumulative order
        const void* s; int off;
        if      (i < 2304) { s = a.encw; off = 0;    }
        else if (i < 2432) { s = a.encb; off = 2304; }
        else if (i < 2560) { s = a.enlg; off = 2432; }
        else if (i < 2688) { s = a.enlb; off = 2560; }
        else if (i < 4224) { s = a.asrc; off = 2688; }
        else if (i < 5760) { s = a.adst; off = 4224; }
        else if (i < 6144) { s = a.bias; off = 5760; }
        else if (i < 6528) { s = a.bng;  off = 6144; }
        else if (i < 6912) { s = a.bnb;  off = 6528; }
        else if (i < 7296) { s = a.bnm;  off = 6912; }
        else if (i < 7680) { s = a.bnv;  off = 7296; }
        else if (i < 7808) { s = a.em1b; off = 7680; }
        else if (i < 7936) { s = a.emlg; off = 7808; }
        else if (i < 8064) { s = a.emlb; off = 7936; }
        else if (i < 8128) { s = a.em2b; off = 8064; }
        else if (i < 8192) { s = a.em3w; off = 8128; }
        else               { s = a.em3b; off = 8192; }
        pool[i] = pread(s, i - off, bf);
        return;
    }
    i -= 8193;
    if (i < 196608) {   // gwt[L][n=512][k=128] = gat_w[L][k][n]
        int L = i >> 16, rem = i & 65535, n = rem >> 7, k = rem & 127;
        gwt[i] = f2b(pread(a.gatw, (size_t)L * 65536 + (size_t)k * 512 + n, bf));
        return;
    }
    i -= 196608;
    if (i < 36864) {    // w1t[n=128][k=288] = em1_w[k][n], zero-pad k>=264
        int n = i / 288, k = i - n * 288;
        w1t[i] = (k < 264) ? f2b(pread(a.em1w, (size_t)k * 128 + n, bf)) : 0;
        return;
    }
    i -= 36864;
    if (i < 8192) {     // w2t[n=64][k=128] = em2_w[k][n]
        int n = i >> 7, k = i & 127;
        w2t[i] = f2b(pread(a.em2w, (size_t)k * 64 + n, bf));
    }
}

// ------------------------------------------------------------ graph build
__global__ void k_graph(const int* __restrict__ ei, const int* __restrict__ shock,
                        float* __restrict__ down, int* __restrict__ deg) {
    int e = blockIdx.x * blockDim.x + threadIdx.x;
    if (e < ETOT) {
        int d = (e < N_EDGES) ? ei[N_EDGES + e] : (e - N_EDGES);
        atomicAdd(&deg[d], 1);
        if (e < N_EDGES && shock[ei[e]] != 0) down[d] = 1.f;
    }
}

__global__ void k_scan(const int* __restrict__ deg, int* __restrict__ row_start) {
    __shared__ int wsum[16];
    __shared__ int wexcl[16];
    __shared__ int tot_s;
    __shared__ int carry_s;
    int tid = threadIdx.x, lane = tid & 63, wid = tid >> 6;
    if (tid == 0) carry_s = 0;
    __syncthreads();
    for (int base = 0; base < N_NODES; base += 1024) {
        int i = base + tid;
        int v = (i < N_NODES) ? deg[i] : 0;
        int inc = v;
#pragma unroll
        for (int off = 1; off < 64; off <<= 1) {
            int t = __shfl_up(inc, off);
            if (lane >= off) inc += t;
        }
        if (lane == 63) wsum[wid] = inc;
        __syncthreads();
        if (wid == 0) {
            int wv = (lane < 16) ? wsum[lane] : 0;
            int winc = wv;
#pragma unroll
            for (int off = 1; off < 16; off <<= 1) {
                int t = __shfl_up(winc, off);
                if (lane >= off) winc += t;
            }
            if (lane < 16) wexcl[lane] = winc - wv;
            if (lane == 15) tot_s = winc;
        }
        __syncthreads();
        int carry = carry_s;
        if (i < N_NODES) row_start[i] = carry + wexcl[wid] + (inc - v);
        __syncthreads();
        if (tid == 0) carry_s = carry + tot_s;
        __syncthreads();
    }
    if (threadIdx.x == 0) row_start[N_NODES] = ETOT;
}

__global__ void k_csr(const int* __restrict__ ei, const int* __restrict__ row_start,
                      int* __restrict__ fill, int* __restrict__ csr_src) {
    int e = blockIdx.x * blockDim.x + threadIdx.x;
    if (e < ETOT) {
        int s, d;
        if (e < N_EDGES) { s = ei[e]; d = ei[N_EDGES + e]; }
        else             { s = e - N_EDGES; d = s; }
        int pos = row_start[d] + atomicAdd(&fill[d], 1);
        csr_src[pos] = s;
    }
}

// ------------------------------------------------------------ encoder -> h bf16
__global__ __launch_bounds__(128) void k_encoder(
        const void* __restrict__ xraw, const int* __restrict__ flag,
        const int* __restrict__ shock, const float* __restrict__ down,
        const float* __restrict__ enc_w, const float* __restrict__ enc_b,
        const float* __restrict__ ln_g, const float* __restrict__ ln_b,
        unsigned short* __restrict__ h) {
    int n = blockIdx.x, c = threadIdx.x;
    __shared__ float xa[18];
    __shared__ float red[4];
    int bf = flag[0];
    if (c < 16)       xa[c]  = pread(xraw, (size_t)n * 16 + c, bf);
    else if (c == 16) xa[16] = (float)shock[n];
    else if (c == 17) xa[17] = down[n];
    __syncthreads();
    float acc = enc_b[c];
#pragma unroll
    for (int k = 0; k < 18; k++) acc = fmaf(xa[k], enc_w[k * HID + c], acc);
    float s = acc, q = acc * acc;
    for (int off = 32; off > 0; off >>= 1) {
        s += __shfl_down(s, off);
        q += __shfl_down(q, off);
    }
    if ((c & 63) == 0) { red[(c >> 6) * 2] = s; red[(c >> 6) * 2 + 1] = q; }
    __syncthreads();
    float S = red[0] + red[2], Q = red[1] + red[3];
    float mu = S * (1.f / 128.f);
    float var = Q * (1.f / 128.f) - mu * mu;
    float rstd = rsqrtf(var + LN_EPS);
    float v = (acc - mu) * rstd * ln_g[c] + ln_b[c];
    h[(size_t)n * HID + c] = f2b(fmaxf(v, 0.f));
}

// ------------------------------------------------------------ GAT GEMM (MFMA)
// xh[50000,512] = h[50000,128] @ W — A bf16 LDS-staged, B(=W^T[n][k]) in regs.
// Block: 256 thr = 4 waves; tile M=64, N=128 (wave w -> n-subtiles 2w,2w+1).
__global__ __launch_bounds__(256, 2) void k_gemm(
        const unsigned short* __restrict__ A, const unsigned short* __restrict__ Wt,
        unsigned short* __restrict__ C) {
    __shared__ __align__(16) unsigned short As[64 * 136];  // stride 136 (272B)
    int t = threadIdx.x;
    int lane = t & 63, w = t >> 6, l15 = lane & 15, q = lane >> 4;
    int m0 = blockIdx.x * 64, n0 = blockIdx.y * 128;

    // B fragments: Wt[n][k], n = n0 + w*32 + nt*16 + l15, k = kt*32 + q*8
    v8s b[2][4];
#pragma unroll
    for (int nt = 0; nt < 2; nt++)
#pragma unroll
        for (int kt = 0; kt < 4; kt++) {
            int n = n0 + w * 32 + nt * 16 + l15;
            b[nt][kt] = *(const v8s*)&Wt[(size_t)n * 128 + kt * 32 + q * 8];
        }
    // stage A tile: 64 rows x 128 cols bf16
#pragma unroll
    for (int it = 0; it < 4; it++) {
        int c = t + it * 256;            // 1024 chunks of 8 bf16
        int row = c >> 4, ch = c & 15;
        v8s val = {0, 0, 0, 0, 0, 0, 0, 0};
        if (m0 + row < N_NODES)
            val = *(const v8s*)&A[(size_t)(m0 + row) * 128 + ch * 8];
        *(v8s*)&As[row * 136 + ch * 8] = val;
    }
    __syncthreads();

    v4f acc[4][2] = {};
#pragma unroll
    for (int kt = 0; kt < 4; kt++)
#pragma unroll
        for (int mt = 0; mt < 4; mt++) {
            v8s a = *(const v8s*)&As[(mt * 16 + l15) * 136 + kt * 32 + q * 8];
            acc[mt][0] = MFMA(a, b[0][kt], acc[mt][0]);
            acc[mt][1] = MFMA(a, b[1][kt], acc[mt][1]);
        }
#pragma unroll
    for (int mt = 0; mt < 4; mt++)
#pragma unroll
        for (int nt = 0; nt < 2; nt++) {
            int col = n0 + w * 32 + nt * 16 + l15;
#pragma unroll
            for (int r = 0; r < 4; r++) {
                int node = m0 + mt * 16 + q * 4 + r;
                if (node < N_NODES)
                    C[(size_t)node * 512 + col] = f2b(acc[mt][nt][r]);
            }
        }
}

// ------------------------------------------------------------ attention logits
__global__ __launch_bounds__(256) void k_logits(
        const unsigned short* __restrict__ xh, const float* __restrict__ asrc,
        const float* __restrict__ adst,
        float* __restrict__ al_src, float* __restrict__ al_dst) {
    int n = blockIdx.x;
    int w = threadIdx.x >> 6;
    int l = threadIdx.x & 63;
    const unsigned short* row = xh + (size_t)n * 512 + w * 128;
    const float* ps = asrc + w * 128;
    const float* pd = adst + w * 128;
    float r0 = b2f(row[l]), r1 = b2f(row[l + 64]);
    float s1 = r0 * ps[l] + r1 * ps[l + 64];
    float s2 = r0 * pd[l] + r1 * pd[l + 64];
    for (int off = 32; off > 0; off >>= 1) {
        s1 += __shfl_down(s1, off);
        s2 += __shfl_down(s2, off);
    }
    if (l == 0) { al_src[n * 4 + w] = s1; al_dst[n * 4 + w] = s2; }
}

// ------------------------------------------------------------ aggregation -> h bf16
__global__ __launch_bounds__(128) void k_aggregate(
        const unsigned short* __restrict__ xh, const float* __restrict__ al_src,
        const float* __restrict__ al_dst,
        const int* __restrict__ row_start, const int* __restrict__ csr_src,
        const float* __restrict__ bias,
        const float* __restrict__ bn_g, const float* __restrict__ bn_b,
        const float* __restrict__ bn_m, const float* __restrict__ bn_v,
        unsigned short* __restrict__ h, int relu_flag) {
    int n = blockIdx.x, c = threadIdx.x;
    int r0 = row_start[n], r1 = row_start[n + 1];
    float ad[4];
#pragma unroll
    for (int hh = 0; hh < 4; hh++) ad[hh] = al_dst[n * 4 + hh];
    float mh[4] = {-1e30f, -1e30f, -1e30f, -1e30f};
    for (int j = r0; j < r1; j++) {
        int s = csr_src[j];
#pragma unroll
        for (int hh = 0; hh < 4; hh++) {
            float a = al_src[s * 4 + hh] + ad[hh];
            a = (a >= 0.f) ? a : NEG * a;
            mh[hh] = fmaxf(mh[hh], a);
        }
    }
    float sh[4] = {0.f, 0.f, 0.f, 0.f};
    float acc[4] = {0.f, 0.f, 0.f, 0.f};
    for (int j = r0; j < r1; j++) {
        int s = csr_src[j];
        const unsigned short* row = xh + (size_t)s * 512 + c;
#pragma unroll
        for (int hh = 0; hh < 4; hh++) {
            float a = al_src[s * 4 + hh] + ad[hh];
            a = (a >= 0.f) ? a : NEG * a;
            float wgt = __expf(a - mh[hh]);
            sh[hh] += wgt;
            acc[hh] += wgt * b2f(row[hh * 128]);
        }
    }
    float v = 0.f;
#pragma unroll
    for (int hh = 0; hh < 4; hh++) v += acc[hh] / (sh[hh] + 1e-16f);
    v = 0.25f * v + bias[c];
    v = (v - bn_m[c]) * rsqrtf(bn_v[c] + LN_EPS) * bn_g[c] + bn_b[c];
    if (relu_flag) v = fmaxf(v, 0.f);
    h[(size_t)n * HID + c] = f2b(v);
}

// ------------------------------------------------------------ edge MLP (MFMA)
// Per block: 64 edges. L1: [64,288]@[288,128] MFMA (K-extended: 256 h + 8 ea
// + 24 zero-pad), +bias, LN, relu. L2: [64,128]@[128,64] MFMA, relu, dot em3.
__global__ __launch_bounds__(256, 2) void k_edgemlp(
        const unsigned short* __restrict__ h, const int* __restrict__ ei,
        const void* __restrict__ eraw, const int* __restrict__ flag,
        const unsigned short* __restrict__ w1t, const unsigned short* __restrict__ w2t,
        const float* __restrict__ em1b, const float* __restrict__ lng,
        const float* __restrict__ lnb, const float* __restrict__ em2b,
        const float* __restrict__ em3w, const float* __restrict__ em3b,
        float* __restrict__ out) {
    __shared__ __align__(16) unsigned short in_s[64 * 296]; // A1; aliased as zs f32
    __shared__ __align__(16) unsigned short za[64 * 136];   // A2 (post-LN bf16)
    __shared__ int   idx_s[64 * 2];
    __shared__ float stats[64 * 2];
    __shared__ float part[4 * 64];
    float* zs = (float*)in_s;                                // [64][132] f32

    int t = threadIdx.x;
    int lane = t & 63, w = t >> 6, l15 = lane & 15, q = lane >> 4;
    int e0 = blockIdx.x * 64;
    int bf = flag[0];

    // persistent B fragments
    v8s b1[2][9];
#pragma unroll
    for (int nt = 0; nt < 2; nt++)
#pragma unroll
        for (int kt = 0; kt < 9; kt++) {
            int n = w * 32 + nt * 16 + l15;
            b1[nt][kt] = *(const v8s*)&w1t[(size_t)n * 288 + kt * 32 + q * 8];
        }
    v8s b2[4];
#pragma unroll
    for (int kt = 0; kt < 4; kt++) {
        int n = w * 16 + l15;
        b2[kt] = *(const v8s*)&w2t[(size_t)n * 128 + kt * 32 + q * 8];
    }

    if (t < 64) {
        idx_s[t * 2]     = ei[e0 + t];
        idx_s[t * 2 + 1] = ei[N_EDGES + e0 + t];
    }
    __syncthreads();

    // gather A1: cols 0..127 h[src], 128..255 h[dst], 256..263 ea, 264..287 zero
    for (int idx = t; idx < 64 * 36; idx += 256) {
        int row = idx / 36, c = idx - row * 36;
        v8s val = {0, 0, 0, 0, 0, 0, 0, 0};
        if (c < 32) {
            int node = idx_s[row * 2 + (c >> 4)];
            val = *(const v8s*)&h[(size_t)node * 128 + (c & 15) * 8];
        } else if (c == 32) {
            size_t eb = (size_t)(e0 + row) * 8;
            if (bf) {
                val = *(const v8s*)((const unsigned short*)eraw + eb);
            } else {
                short tmp[8];
#pragma unroll
                for (int j = 0; j < 8; j++)
                    tmp[j] = (short)f2b(((const float*)eraw)[eb + j]);
                val = *(const v8s*)tmp;
            }
        }
        *(v8s*)&in_s[row * 296 + c * 8] = val;
    }
    __syncthreads();

    // layer 1 MFMA: wave w covers all 64 edges x 32 cols (nt 0..1)
    v4f acc1[4][2] = {};
#pragma unroll
    for (int kt = 0; kt < 9; kt++)
#pragma unroll
        for (int mt = 0; mt < 4; mt++) {
            v8s a = *(const v8s*)&in_s[(mt * 16 + l15) * 296 + kt * 32 + q * 8];
            acc1[mt][0] = MFMA(a, b1[0][kt], acc1[mt][0]);
            acc1[mt][1] = MFMA(a, b1[1][kt], acc1[mt][1]);
        }
    __syncthreads();   // all A1 reads done — safe to overwrite as zs

    // epilogue 1: +bias -> zs (pre-LN)
#pragma unroll
    for (int mt = 0; mt < 4; mt++)
#pragma unroll
        for (int nt = 0; nt < 2; nt++) {
            int col = w * 32 + nt * 16 + l15;
            float bc = em1b[col];
#pragma unroll
            for (int r = 0; r < 4; r++) {
                int row = mt * 16 + q * 4 + r;
                zs[row * 132 + col] = acc1[mt][nt][r] + bc;
            }
        }
    __syncthreads();

    // LN stats: 4 threads per edge
    {
        int e = t >> 2, p = t & 3;
        float s = 0.f, qq = 0.f;
#pragma unroll
        for (int i = 0; i < 32; i++) {
            float v = zs[e * 132 + p * 32 + i];
            s += v; qq += v * v;
        }
        s  += __shfl_down(s, 2);  s  += __shfl_down(s, 1);
        qq += __shfl_down(qq, 2); qq += __shfl_down(qq, 1);
        if (p == 0) {
            float mu = s * (1.f / 128.f);
            float var = qq * (1.f / 128.f) - mu * mu;
            stats[e * 2] = mu;
            stats[e * 2 + 1] = rsqrtf(var + LN_EPS);
        }
    }
    __syncthreads();

    // normalize + relu -> za bf16 (A-layout for layer 2)
    for (int idx = t; idx < 64 * 128; idx += 256) {
        int e = idx >> 7, c = idx & 127;
        float v = (zs[e * 132 + c] - stats[e * 2]) * stats[e * 2 + 1] * lng[c] + lnb[c];
        za[e * 136 + c] = f2b(fmaxf(v, 0.f));
    }
    __syncthreads();

    // layer 2 MFMA: wave w -> n-tile w (16 cols), all 64 edges
    v4f acc2[4] = {};
#pragma unroll
    for (int kt = 0; kt < 4; kt++)
#pragma unroll
        for (int mt = 0; mt < 4; mt++) {
            v8s a = *(const v8s*)&za[(mt * 16 + l15) * 136 + kt * 32 + q * 8];
            acc2[mt] = MFMA(a, b2[kt], acc2[mt]);
        }

    // epilogue 2: relu, * em3_w, reduce over cols
    {
        int col = w * 16 + l15;
        float b2c = em2b[col], w3c = em3w[col];
#pragma unroll
        for (int mt = 0; mt < 4; mt++)
#pragma unroll
            for (int r = 0; r < 4; r++) {
                float v = fmaxf(acc2[mt][r] + b2c, 0.f) * w3c;
                v += __shfl_down(v, 8);
                v += __shfl_down(v, 4);
                v += __shfl_down(v, 2);
                v += __shfl_down(v, 1);
                if (l15 == 0) part[w * 64 + mt * 16 + q * 4 + r] = v;
            }
    }
    __syncthreads();
    if (t < 64)
        out[e0 + t] = part[t] + part[64 + t] + part[128 + t] + part[192 + t]
                    + em3b[0];
}

// ------------------------------------------------------------ launch
extern "C" __attribute__((visibility("default")))
void kernel_launch(void* const* d_in, const int* in_sizes, int n_in,
                   void* d_out, int out_size, void* d_ws, size_t ws_size,
                   hipStream_t stream) {
    float* out = (float*)d_out;

    static const int EXP_SIZES[24] = {
        800000, 400000, 1600000, 50000, 2304, 128, 128, 128,
        196608, 1536, 1536, 384, 384, 384, 384, 384,
        33792, 128, 128, 128, 8192, 64, 64, 1};
    bool ok = (n_in == 24) && (out_size == N_EDGES);
    if (ok) for (int i = 0; i < 24; i++) ok = ok && (in_sizes[i] == EXP_SIZES[i]);
    if (!ok) {
        k_fill<<<(out_size + 255) / 256, 256, 0, stream>>>(out, out_size, 4.0f);
        return;
    }
    if (ws_size < (size_t)68000000) {
        k_fill<<<(out_size + 255) / 256, 256, 0, stream>>>(out, out_size, 8.0f);
        return;
    }

    const int* ei    = (const int*)d_in[1];
    const int* shock = (const int*)d_in[3];

    char* ws = (char*)d_ws;
    unsigned short* h_bf  = (unsigned short*)(ws + 0);          // 12,800,000
    unsigned short* xh    = (unsigned short*)(ws + 12800000);   // 51,200,000
    float* al_s    = (float*)(ws + 64000000);                   // 800,000
    float* al_d    = (float*)(ws + 64800000);                   // 800,000
    float* down    = (float*)(ws + 65600000);                   // 200,000
    int*   deg     = (int*)  (ws + 65800000);                   // 200,000
    int*   row_st  = (int*)  (ws + 66000000);                   // 200,064
    int*   fill    = (int*)  (ws + 66200064);                   // 200,000
    int*   csr_src = (int*)  (ws + 66400064);                   // 1,000,000
    int*   flag    = (int*)  (ws + 67400064);                   // 64
    unsigned short* gwt = (unsigned short*)(ws + 67400128);     // 393,216
    unsigned short* w1t = (unsigned short*)(ws + 67793344);     // 73,728
    unsigned short* w2t = (unsigned short*)(ws + 67867072);     // 16,384
    float* pool    = (float*)(ws + 67883456);                   // 32,772

    // pool offsets (floats)
    float* cencw = pool + 0;    float* cencb = pool + 2304;
    float* cenlg = pool + 2432; float* cenlb = pool + 2560;
    float* casrc = pool + 2688; float* cadst = pool + 4224;
    float* cbias = pool + 5760; float* cbng  = pool + 6144;
    float* cbnb  = pool + 6528; float* cbnm  = pool + 6912;
    float* cbnv  = pool + 7296; float* cem1b = pool + 7680;
    float* cemlg = pool + 7808; float* cemlb = pool + 7936;
    float* cem2b = pool + 8064; float* cem3w = pool + 8128;
    float* cem3b = pool + 8192;

    k_detect<<<1, 64, 0, stream>>>((const unsigned short*)d_in[0], flag);

    PrepArgs pa;
    pa.encw = d_in[4];  pa.encb = d_in[5];  pa.enlg = d_in[6];  pa.enlb = d_in[7];
    pa.gatw = d_in[8];  pa.asrc = d_in[9];  pa.adst = d_in[10]; pa.bias = d_in[11];
    pa.bng  = d_in[12]; pa.bnb  = d_in[13]; pa.bnm  = d_in[14]; pa.bnv  = d_in[15];
    pa.em1w = d_in[16]; pa.em1b = d_in[17]; pa.emlg = d_in[18]; pa.emlb = d_in[19];
    pa.em2w = d_in[20]; pa.em2b = d_in[21]; pa.em3w = d_in[22]; pa.em3b = d_in[23];
    k_prep<<<(PREP_ITEMS + 255) / 256, 256, 0, stream>>>(
        pa, pool, gwt, w1t, w2t, down, deg, fill, flag);

    k_graph<<<(ETOT + 255) / 256, 256, 0, stream>>>(ei, shock, down, deg);
    k_scan<<<1, 1024, 0, stream>>>(deg, row_st);
    k_csr<<<(ETOT + 255) / 256, 256, 0, stream>>>(ei, row_st, fill, csr_src);
    k_encoder<<<N_NODES, 128, 0, stream>>>(d_in[0], flag, shock, down,
                                           cencw, cencb, cenlg, cenlb, h_bf);
    for (int i = 0; i < 3; i++) {
        k_gemm<<<dim3(782, 4), 256, 0, stream>>>(
            h_bf, gwt + (size_t)i * 65536, xh);
        k_logits<<<N_NODES, 256, 0, stream>>>(
            xh, casrc + i * 512, cadst + i * 512, al_s, al_d);
        k_aggregate<<<N_NODES, 128, 0, stream>>>(
            xh, al_s, al_d, row_st, csr_src,
            cbias + i * 128, cbng + i * 128, cbnb + i * 128,
            cbnm + i * 128, cbnv + i * 128, h_bf, (i < 2) ? 1 : 0);
    }
    k_edgemlp<<<N_EDGES / 64, 256, 0, stream>>>(
        h_bf, ei, d_in[2], flag, w1t, w2t,
        cem1b, cemlg, cemlb, cem2b, cem3w, cem3b, out);
}

// Round 5
// 641.514 us; speedup vs baseline: 2.7578x; 1.0685x over previous
//
#include <hip/hip_runtime.h>
#include <hip/hip_bf16.h>

// ShockPropagationGNN — round 4: occupancy + fusion.
// - edgemlp: LN in registers (no f32 LDS round-trip), za aliased over in_s,
//   LDS 57->42KB (3 blocks/CU), bank-conflict LN loop removed.
// - logits fused into gemm epilogue (block = one head => no atomics).
// - aggregate: wave-per-node, 16B row loads, shfl head-mean.
// - scan: single-pass block scan.

#define N_NODES 50000
#define N_EDGES 200000
#define ETOT    (N_EDGES + N_NODES)
#define HID     128
#define LN_EPS  1e-5f
#define NEG     0.2f

typedef __hip_bfloat16 bf16;
typedef __attribute__((ext_vector_type(8))) short v8s;
typedef __attribute__((ext_vector_type(4))) float v4f;
#define MFMA(a, b, c) __builtin_amdgcn_mfma_f32_16x16x32_bf16(a, b, c, 0, 0, 0)

__device__ __forceinline__ float b2f(unsigned short s) {
    return __uint_as_float(((unsigned int)s) << 16);
}
__device__ __forceinline__ unsigned short f2b(float f) {
    __hip_bfloat16 h = __float2bfloat16(f);
    return *reinterpret_cast<unsigned short*>(&h);
}
__device__ __forceinline__ float pread(const void* p, size_t i, int isbf) {
    if (isbf) return b2f(((const unsigned short*)p)[i]);
    return ((const float*)p)[i];
}

__global__ void k_fill(float* out, int n, float v) {
    int i = blockIdx.x * blockDim.x + threadIdx.x;
    if (i < n) out[i] = v;
}

// ------------------------------------------------------------ dtype detect
__global__ void k_detect(const unsigned short* __restrict__ xbuf,
                         int* __restrict__ flag) {
    int sane = 0;
    for (int j = threadIdx.x; j < 4096; j += 64) {
        unsigned short v = xbuf[2 * j];
        int e = (v >> 7) & 0xFF;
        if (v == 0 || (e > 96 && e < 160)) sane++;
    }
    for (int off = 32; off > 0; off >>= 1) sane += __shfl_down(sane, off);
    if (threadIdx.x == 0) flag[0] = (sane * 10 >= 4096 * 9) ? 1 : 0;
}

// ------------------------------------------------------------ prep (fused)
struct PrepArgs {
    const void *encw, *encb, *enlg, *enlb, *gatw, *asrc, *adst, *bias,
               *bng, *bnb, *bnm, *bnv, *em1w, *em1b, *emlg, *emlb,
               *em2w, *em2b, *em3w, *em3b;
};
#define PREP_ITEMS (150000 + 8193 + 196608 + 36864 + 8192)
__global__ void k_prep(PrepArgs a, float* __restrict__ pool,
                       unsigned short* __restrict__ gwt,
                       unsigned short* __restrict__ w1t,
                       unsigned short* __restrict__ w2t,
                       float* __restrict__ down, int* __restrict__ deg,
                       int* __restrict__ fill, const int* __restrict__ flag) {
    int i = blockIdx.x * 256 + threadIdx.x;
    int bf = flag[0];
    if (i < 150000) {
        int which = i / 50000, idx = i - which * 50000;
        if (which == 0) down[idx] = 0.f;
        else if (which == 1) deg[idx] = 0;
        else fill[idx] = 0;
        return;
    }
    i -= 150000;
    if (i < 8193) {
        const void* s; int off;
        if      (i < 2304) { s = a.encw; off = 0;    }
        else if (i < 2432) { s = a.encb; off = 2304; }
        else if (i < 2560) { s = a.enlg; off = 2432; }
        else if (i < 2688) { s = a.enlb; off = 2560; }
        else if (i < 4224) { s = a.asrc; off = 2688; }
        else if (i < 5760) { s = a.adst; off = 4224; }
        else if (i < 6144) { s = a.bias; off = 5760; }
        else if (i < 6528) { s = a.bng;  off = 6144; }
        else if (i < 6912) { s = a.bnb;  off = 6528; }
        else if (i < 7296) { s = a.bnm;  off = 6912; }
        else if (i < 7680) { s = a.bnv;  off = 7296; }
        else if (i < 7808) { s = a.em1b; off = 7680; }
        else if (i < 7936) { s = a.emlg; off = 7808; }
        else if (i < 8064) { s = a.emlb; off = 7936; }
        else if (i < 8128) { s = a.em2b; off = 8064; }
        else if (i < 8192) { s = a.em3w; off = 8128; }
        else               { s = a.em3b; off = 8192; }
        pool[i] = pread(s, i - off, bf);
        return;
    }
    i -= 8193;
    if (i < 196608) {   // gwt[L][n=512][k=128] = gat_w[L][k][n]
        int L = i >> 16, rem = i & 65535, n = rem >> 7, k = rem & 127;
        gwt[i] = f2b(pread(a.gatw, (size_t)L * 65536 + (size_t)k * 512 + n, bf));
        return;
    }
    i -= 196608;
    if (i < 36864) {    // w1t[n=128][k=288] = em1_w[k][n], zero-pad k>=264
        int n = i / 288, k = i - n * 288;
        w1t[i] = (k < 264) ? f2b(pread(a.em1w, (size_t)k * 128 + n, bf)) : 0;
        return;
    }
    i -= 36864;
    if (i < 8192) {     // w2t[n=64][k=128] = em2_w[k][n]
        int n = i >> 7, k = i & 127;
        w2t[i] = f2b(pread(a.em2w, (size_t)k * 64 + n, bf));
    }
}

// ------------------------------------------------------------ graph build
__global__ void k_graph(const int* __restrict__ ei, const int* __restrict__ shock,
                        float* __restrict__ down, int* __restrict__ deg) {
    int e = blockIdx.x * blockDim.x + threadIdx.x;
    if (e < ETOT) {
        int d = (e < N_EDGES) ? ei[N_EDGES + e] : (e - N_EDGES);
        atomicAdd(&deg[d], 1);
        if (e < N_EDGES && shock[ei[e]] != 0) down[d] = 1.f;
    }
}

// single-block single-pass scan: 49 elems/thread, one block scan
__global__ __launch_bounds__(1024) void k_scan(
        const int* __restrict__ deg, int* __restrict__ row_start) {
    __shared__ int wsum[16];
    __shared__ int wexcl[16];
    const int PER = 49;     // 1024*49 = 50176 >= 50000
    int t = threadIdx.x, lane = t & 63, wid = t >> 6;
    int base = t * PER;
    int tot = 0;
    for (int i = 0; i < PER; i++) {
        int idx = base + i;
        if (idx < N_NODES) tot += deg[idx];
    }
    int inc = tot;
#pragma unroll
    for (int off = 1; off < 64; off <<= 1) {
        int v = __shfl_up(inc, off);
        if (lane >= off) inc += v;
    }
    if (lane == 63) wsum[wid] = inc;
    __syncthreads();
    if (wid == 0) {
        int wv = (lane < 16) ? wsum[lane] : 0;
        int winc = wv;
#pragma unroll
        for (int off = 1; off < 16; off <<= 1) {
            int v = __shfl_up(winc, off);
            if (lane >= off) winc += v;
        }
        if (lane < 16) wexcl[lane] = winc - wv;
    }
    __syncthreads();
    int run = wexcl[wid] + (inc - tot);
    for (int i = 0; i < PER; i++) {
        int idx = base + i;
        if (idx < N_NODES) {
            row_start[idx] = run;
            run += deg[idx];
        }
    }
    if (t == 0) row_start[N_NODES] = ETOT;
}

__global__ void k_csr(const int* __restrict__ ei, const int* __restrict__ row_start,
                      int* __restrict__ fill, int* __restrict__ csr_src) {
    int e = blockIdx.x * blockDim.x + threadIdx.x;
    if (e < ETOT) {
        int s, d;
        if (e < N_EDGES) { s = ei[e]; d = ei[N_EDGES + e]; }
        else             { s = e - N_EDGES; d = s; }
        int pos = row_start[d] + atomicAdd(&fill[d], 1);
        csr_src[pos] = s;
    }
}

// ------------------------------------------------------------ encoder -> h bf16
__global__ __launch_bounds__(128) void k_encoder(
        const void* __restrict__ xraw, const int* __restrict__ flag,
        const int* __restrict__ shock, const float* __restrict__ down,
        const float* __restrict__ enc_w, const float* __restrict__ enc_b,
        const float* __restrict__ ln_g, const float* __restrict__ ln_b,
        unsigned short* __restrict__ h) {
    int n = blockIdx.x, c = threadIdx.x;
    __shared__ float xa[18];
    __shared__ float red[4];
    int bf = flag[0];
    if (c < 16)       xa[c]  = pread(xraw, (size_t)n * 16 + c, bf);
    else if (c == 16) xa[16] = (float)shock[n];
    else if (c == 17) xa[17] = down[n];
    __syncthreads();
    float acc = enc_b[c];
#pragma unroll
    for (int k = 0; k < 18; k++) acc = fmaf(xa[k], enc_w[k * HID + c], acc);
    float s = acc, q = acc * acc;
    for (int off = 32; off > 0; off >>= 1) {
        s += __shfl_down(s, off);
        q += __shfl_down(q, off);
    }
    if ((c & 63) == 0) { red[(c >> 6) * 2] = s; red[(c >> 6) * 2 + 1] = q; }
    __syncthreads();
    float S = red[0] + red[2], Q = red[1] + red[3];
    float mu = S * (1.f / 128.f);
    float var = Q * (1.f / 128.f) - mu * mu;
    float rstd = rsqrtf(var + LN_EPS);
    float v = (acc - mu) * rstd * ln_g[c] + ln_b[c];
    h[(size_t)n * HID + c] = f2b(fmaxf(v, 0.f));
}

// ------------------------------------------------------------ GAT GEMM + logits
// Block (bx, by): nodes bx*64..+63, cols by*128..+127 == head by exactly.
// After C write, reduce al_src/al_dst for this head in-block (no atomics).
__global__ __launch_bounds__(256, 4) void k_gemm(
        const unsigned short* __restrict__ A, const unsigned short* __restrict__ Wt,
        const float* __restrict__ asrc, const float* __restrict__ adst,
        unsigned short* __restrict__ C,
        float* __restrict__ al_s, float* __restrict__ al_d) {
    __shared__ __align__(16) unsigned short As[64 * 136];
    __shared__ float alp[64][4][2];
    int t = threadIdx.x;
    int lane = t & 63, w = t >> 6, l15 = lane & 15, q = lane >> 4;
    int m0 = blockIdx.x * 64, n0 = blockIdx.y * 128, head = blockIdx.y;

    v8s b[2][4];
#pragma unroll
    for (int nt = 0; nt < 2; nt++)
#pragma unroll
        for (int kt = 0; kt < 4; kt++) {
            int n = n0 + w * 32 + nt * 16 + l15;
            b[nt][kt] = *(const v8s*)&Wt[(size_t)n * 128 + kt * 32 + q * 8];
        }
#pragma unroll
    for (int it = 0; it < 4; it++) {
        int c = t + it * 256;
        int row = c >> 4, ch = c & 15;
        v8s val = {0, 0, 0, 0, 0, 0, 0, 0};
        if (m0 + row < N_NODES)
            val = *(const v8s*)&A[(size_t)(m0 + row) * 128 + ch * 8];
        *(v8s*)&As[row * 136 + ch * 8] = val;
    }
    __syncthreads();

    v4f acc[4][2] = {};
#pragma unroll
    for (int kt = 0; kt < 4; kt++)
#pragma unroll
        for (int mt = 0; mt < 4; mt++) {
            v8s a = *(const v8s*)&As[(mt * 16 + l15) * 136 + kt * 32 + q * 8];
            acc[mt][0] = MFMA(a, b[0][kt], acc[mt][0]);
            acc[mt][1] = MFMA(a, b[1][kt], acc[mt][1]);
        }
#pragma unroll
    for (int mt = 0; mt < 4; mt++)
#pragma unroll
        for (int nt = 0; nt < 2; nt++) {
            int col = n0 + w * 32 + nt * 16 + l15;
#pragma unroll
            for (int r = 0; r < 4; r++) {
                int node = m0 + mt * 16 + q * 4 + r;
                if (node < N_NODES)
                    C[(size_t)node * 512 + col] = f2b(acc[mt][nt][r]);
            }
        }

    // fused logits: al[node][head] = sum over 128 cols
    float ps0 = asrc[n0 + w * 32 + l15], ps1 = asrc[n0 + w * 32 + 16 + l15];
    float pd0 = adst[n0 + w * 32 + l15], pd1 = adst[n0 + w * 32 + 16 + l15];
#pragma unroll
    for (int mt = 0; mt < 4; mt++)
#pragma unroll
        for (int r = 0; r < 4; r++) {
            float vs = acc[mt][0][r] * ps0 + acc[mt][1][r] * ps1;
            float vd = acc[mt][0][r] * pd0 + acc[mt][1][r] * pd1;
#pragma unroll
            for (int off = 1; off < 16; off <<= 1) {
                vs += __shfl_xor(vs, off);
                vd += __shfl_xor(vd, off);
            }
            if (l15 == 0) {
                alp[mt * 16 + q * 4 + r][w][0] = vs;
                alp[mt * 16 + q * 4 + r][w][1] = vd;
            }
        }
    __syncthreads();
    if (t < 64) {
        int node = m0 + t;
        if (node < N_NODES) {
            float ss = alp[t][0][0] + alp[t][1][0] + alp[t][2][0] + alp[t][3][0];
            float sd = alp[t][0][1] + alp[t][1][1] + alp[t][2][1] + alp[t][3][1];
            al_s[node * 4 + head] = ss;
            al_d[node * 4 + head] = sd;
        }
    }
}

// ------------------------------------------------------------ aggregation
// One wave per node (4 nodes / 256-thr block). Lane l: head l>>4,
// channels (l&15)*8..+7 -> one 16B xh read per edge per lane.
__global__ __launch_bounds__(256) void k_aggregate(
        const unsigned short* __restrict__ xh, const float* __restrict__ al_src,
        const float* __restrict__ al_dst,
        const int* __restrict__ row_start, const int* __restrict__ csr_src,
        const float* __restrict__ bias,
        const float* __restrict__ bn_g, const float* __restrict__ bn_b,
        const float* __restrict__ bn_m, const float* __restrict__ bn_v,
        unsigned short* __restrict__ h, int relu_flag) {
    int w = threadIdx.x >> 6, l = threadIdx.x & 63;
    int n = blockIdx.x * 4 + w;
    int hh = l >> 4, c8 = l & 15;
    int r0 = row_start[n], r1 = row_start[n + 1];
    float ad = al_dst[n * 4 + hh];
    float m = -1e30f;
    for (int j = r0; j < r1; j++) {
        int s = csr_src[j];
        float a = al_src[s * 4 + hh] + ad;
        a = (a >= 0.f) ? a : NEG * a;
        m = fmaxf(m, a);
    }
    float sh = 0.f;
    float acc[8] = {};
    for (int j = r0; j < r1; j++) {
        int s = csr_src[j];
        float a = al_src[s * 4 + hh] + ad;
        a = (a >= 0.f) ? a : NEG * a;
        float we = __expf(a - m);
        sh += we;
        v8s row = *(const v8s*)&xh[(size_t)s * 512 + l * 8];
#pragma unroll
        for (int i = 0; i < 8; i++)
            acc[i] = fmaf(we, b2f((unsigned short)row[i]), acc[i]);
    }
    float inv = 1.f / (sh + 1e-16f);
#pragma unroll
    for (int i = 0; i < 8; i++) {
        acc[i] *= inv;
        acc[i] += __shfl_xor(acc[i], 16);
        acc[i] += __shfl_xor(acc[i], 32);
    }
    if (hh == 0) {
        int cbase = c8 * 8;
        short o[8];
#pragma unroll
        for (int i = 0; i < 8; i++) {
            int c = cbase + i;
            float v = 0.25f * acc[i] + bias[c];
            v = (v - bn_m[c]) * rsqrtf(bn_v[c] + LN_EPS) * bn_g[c] + bn_b[c];
            if (relu_flag) v = fmaxf(v, 0.f);
            o[i] = (short)f2b(v);
        }
        *(v8s*)&h[(size_t)n * 128 + cbase] = *(const v8s*)o;
    }
}

// ------------------------------------------------------------ edge MLP (MFMA)
// 64 edges/block. LN stats via shfl from register acc1 (no f32 LDS pass);
// za (bf16 post-LN) aliases in_s. LDS ~42KB -> 3 blocks/CU.
__global__ __launch_bounds__(256, 3) void k_edgemlp(
        const unsigned short* __restrict__ h, const int* __restrict__ ei,
        const void* __restrict__ eraw, const int* __restrict__ flag,
        const unsigned short* __restrict__ w1t, const unsigned short* __restrict__ w2t,
        const float* __restrict__ em1b, const float* __restrict__ lng,
        const float* __restrict__ lnb, const float* __restrict__ em2b,
        const float* __restrict__ em3w, const float* __restrict__ em3b,
        float* __restrict__ out) {
    __shared__ __align__(16) unsigned short in_s[64 * 296]; // 37888B; za aliases
    __shared__ float sums[64][4][2];   // per-edge per-wave (sum, sumsq)
    __shared__ float stats[64][2];     // (mu, rstd)
    __shared__ int   idx_s[128];
    __shared__ float part[4][64];
    unsigned short* za = in_s;         // 64*136 shorts = 8704 <= 18944

    int t = threadIdx.x;
    int lane = t & 63, w = t >> 6, l15 = lane & 15, q = lane >> 4;
    int e0 = blockIdx.x * 64;
    int bf = flag[0];

    v8s b1[2][9];
#pragma unroll
    for (int nt = 0; nt < 2; nt++)
#pragma unroll
        for (int kt = 0; kt < 9; kt++) {
            int n = w * 32 + nt * 16 + l15;
            b1[nt][kt] = *(const v8s*)&w1t[(size_t)n * 288 + kt * 32 + q * 8];
        }
    v8s b2[4];
#pragma unroll
    for (int kt = 0; kt < 4; kt++) {
        int n = w * 16 + l15;
        b2[kt] = *(const v8s*)&w2t[(size_t)n * 128 + kt * 32 + q * 8];
    }
    // LN affine params for this thread's two columns
    int c0 = w * 32 + l15, c1 = c0 + 16;
    float bc0 = em1b[c0], bc1 = em1b[c1];
    float lg0 = lng[c0], lg1 = lng[c1], lb0 = lnb[c0], lb1 = lnb[c1];

    if (t < 64) {
        idx_s[t * 2]     = ei[e0 + t];
        idx_s[t * 2 + 1] = ei[N_EDGES + e0 + t];
    }
    __syncthreads();

    // gather A1: cols 0..127 h[src], 128..255 h[dst], 256..263 ea, 264..287 0
    for (int idx = t; idx < 64 * 36; idx += 256) {
        int row = idx / 36, c = idx - row * 36;
        v8s val = {0, 0, 0, 0, 0, 0, 0, 0};
        if (c < 32) {
            int node = idx_s[row * 2 + (c >> 4)];
            val = *(const v8s*)&h[(size_t)node * 128 + (c & 15) * 8];
        } else if (c == 32) {
            size_t eb = (size_t)(e0 + row) * 8;
            if (bf) {
                val = *(const v8s*)((const unsigned short*)eraw + eb);
            } else {
                short tmp[8];
#pragma unroll
                for (int j = 0; j < 8; j++)
                    tmp[j] = (short)f2b(((const float*)eraw)[eb + j]);
                val = *(const v8s*)tmp;
            }
        }
        *(v8s*)&in_s[row * 296 + c * 8] = val;
    }
    __syncthreads();

    // layer 1 MFMA
    v4f acc1[4][2] = {};
#pragma unroll
    for (int kt = 0; kt < 9; kt++)
#pragma unroll
        for (int mt = 0; mt < 4; mt++) {
            v8s a = *(const v8s*)&in_s[(mt * 16 + l15) * 296 + kt * 32 + q * 8];
            acc1[mt][0] = MFMA(a, b1[0][kt], acc1[mt][0]);
            acc1[mt][1] = MFMA(a, b1[1][kt], acc1[mt][1]);
        }

    // LN stats from registers: per (mt,r) row, reduce (val, val^2) over l15
#pragma unroll
    for (int mt = 0; mt < 4; mt++)
#pragma unroll
        for (int r = 0; r < 4; r++) {
            float v0 = acc1[mt][0][r] + bc0;
            float v1 = acc1[mt][1][r] + bc1;
            float s = v0 + v1;
            float qq = v0 * v0 + v1 * v1;
#pragma unroll
            for (int off = 1; off < 16; off <<= 1) {
                s  += __shfl_xor(s, off);
                qq += __shfl_xor(qq, off);
            }
            if (l15 == 0) {
                sums[mt * 16 + q * 4 + r][w][0] = s;
                sums[mt * 16 + q * 4 + r][w][1] = qq;
            }
        }
    __syncthreads();   // also: all in_s reads done -> za may overwrite
    if (t < 64) {
        float S = sums[t][0][0] + sums[t][1][0] + sums[t][2][0] + sums[t][3][0];
        float Q = sums[t][0][1] + sums[t][1][1] + sums[t][2][1] + sums[t][3][1];
        float mu = S * (1.f / 128.f);
        float var = Q * (1.f / 128.f) - mu * mu;
        stats[t][0] = mu;
        stats[t][1] = rsqrtf(var + LN_EPS);
    }
    __syncthreads();

    // normalize + relu from registers -> za bf16
#pragma unroll
    for (int mt = 0; mt < 4; mt++)
#pragma unroll
        for (int r = 0; r < 4; r++) {
            int row = mt * 16 + q * 4 + r;
            float mu = stats[row][0], rstd = stats[row][1];
            float z0 = (acc1[mt][0][r] + bc0 - mu) * rstd * lg0 + lb0;
            float z1 = (acc1[mt][1][r] + bc1 - mu) * rstd * lg1 + lb1;
            za[row * 136 + c0] = f2b(fmaxf(z0, 0.f));
            za[row * 136 + c1] = f2b(fmaxf(z1, 0.f));
        }
    __syncthreads();

    // layer 2 MFMA: wave w -> cols w*16..+15
    v4f acc2[4] = {};
#pragma unroll
    for (int kt = 0; kt < 4; kt++)
#pragma unroll
        for (int mt = 0; mt < 4; mt++) {
            v8s a = *(const v8s*)&za[(mt * 16 + l15) * 136 + kt * 32 + q * 8];
            acc2[mt] = MFMA(a, b2[kt], acc2[mt]);
        }

    // epilogue 2: relu, * em3_w, reduce over cols
    {
        int col = w * 16 + l15;
        float b2c = em2b[col], w3c = em3w[col];
#pragma unroll
        for (int mt = 0; mt < 4; mt++)
#pragma unroll
            for (int r = 0; r < 4; r++) {
                float v = fmaxf(acc2[mt][r] + b2c, 0.f) * w3c;
#pragma unroll
                for (int off = 1; off < 16; off <<= 1) v += __shfl_xor(v, off);
                if (l15 == 0) part[w][mt * 16 + q * 4 + r] = v;
            }
    }
    __syncthreads();
    if (t < 64)
        out[e0 + t] = part[0][t] + part[1][t] + part[2][t] + part[3][t]
                    + em3b[0];
}

// ------------------------------------------------------------ launch
extern "C" __attribute__((visibility("default")))
void kernel_launch(void* const* d_in, const int* in_sizes, int n_in,
                   void* d_out, int out_size, void* d_ws, size_t ws_size,
                   hipStream_t stream) {
    float* out = (float*)d_out;

    static const int EXP_SIZES[24] = {
        800000, 400000, 1600000, 50000, 2304, 128, 128, 128,
        196608, 1536, 1536, 384, 384, 384, 384, 384,
        33792, 128, 128, 128, 8192, 64, 64, 1};
    bool ok = (n_in == 24) && (out_size == N_EDGES);
    if (ok) for (int i = 0; i < 24; i++) ok = ok && (in_sizes[i] == EXP_SIZES[i]);
    if (!ok) {
        k_fill<<<(out_size + 255) / 256, 256, 0, stream>>>(out, out_size, 4.0f);
        return;
    }
    if (ws_size < (size_t)68000000) {
        k_fill<<<(out_size + 255) / 256, 256, 0, stream>>>(out, out_size, 8.0f);
        return;
    }

    const int* ei    = (const int*)d_in[1];
    const int* shock = (const int*)d_in[3];

    char* ws = (char*)d_ws;
    unsigned short* h_bf  = (unsigned short*)(ws + 0);          // 12,800,000
    unsigned short* xh    = (unsigned short*)(ws + 12800000);   // 51,200,000
    float* al_s    = (float*)(ws + 64000000);                   // 800,000
    float* al_d    = (float*)(ws + 64800000);                   // 800,000
    float* down    = (float*)(ws + 65600000);                   // 200,000
    int*   deg     = (int*)  (ws + 65800000);                   // 200,000
    int*   row_st  = (int*)  (ws + 66000000);                   // 200,064
    int*   fill    = (int*)  (ws + 66200064);                   // 200,000
    int*   csr_src = (int*)  (ws + 66400064);                   // 1,000,000
    int*   flag    = (int*)  (ws + 67400064);                   // 64
    unsigned short* gwt = (unsigned short*)(ws + 67400128);     // 393,216
    unsigned short* w1t = (unsigned short*)(ws + 67793344);     // 73,728
    unsigned short* w2t = (unsigned short*)(ws + 67867072);     // 16,384
    float* pool    = (float*)(ws + 67883456);                   // 32,772 floats

    float* cencw = pool + 0;    float* cencb = pool + 2304;
    float* cenlg = pool + 2432; float* cenlb = pool + 2560;
    float* casrc = pool + 2688; float* cadst = pool + 4224;
    float* cbias = pool + 5760; float* cbng  = pool + 6144;
    float* cbnb  = pool + 6528; float* cbnm  = pool + 6912;
    float* cbnv  = pool + 7296; float* cem1b = pool + 7680;
    float* cemlg = pool + 7808; float* cemlb = pool + 7936;
    float* cem2b = pool + 8064; float* cem3w = pool + 8128;
    float* cem3b = pool + 8192;

    k_detect<<<1, 64, 0, stream>>>((const unsigned short*)d_in[0], flag);

    PrepArgs pa;
    pa.encw = d_in[4];  pa.encb = d_in[5];  pa.enlg = d_in[6];  pa.enlb = d_in[7];
    pa.gatw = d_in[8];  pa.asrc = d_in[9];  pa.adst = d_in[10]; pa.bias = d_in[11];
    pa.bng  = d_in[12]; pa.bnb  = d_in[13]; pa.bnm  = d_in[14]; pa.bnv  = d_in[15];
    pa.em1w = d_in[16]; pa.em1b = d_in[17]; pa.emlg = d_in[18]; pa.emlb = d_in[19];
    pa.em2w = d_in[20]; pa.em2b = d_in[21]; pa.em3w = d_in[22]; pa.em3b = d_in[23];
    k_prep<<<(PREP_ITEMS + 255) / 256, 256, 0, stream>>>(
        pa, pool, gwt, w1t, w2t, down, deg, fill, flag);

    k_graph<<<(ETOT + 255) / 256, 256, 0, stream>>>(ei, shock, down, deg);
    k_scan<<<1, 1024, 0, stream>>>(deg, row_st);
    k_csr<<<(ETOT + 255) / 256, 256, 0, stream>>>(ei, row_st, fill, csr_src);
    k_encoder<<<N_NODES, 128, 0, stream>>>(d_in[0], flag, shock, down,
                                           cencw, cencb, cenlg, cenlb, h_bf);
    for (int i = 0; i < 3; i++) {
        k_gemm<<<dim3(782, 4), 256, 0, stream>>>(
            h_bf, gwt + (size_t)i * 65536, casrc + i * 512, cadst + i * 512,
            xh, al_s, al_d);
        k_aggregate<<<N_NODES / 4, 256, 0, stream>>>(
            xh, al_s, al_d, row_st, csr_src,
            cbias + i * 128, cbng + i * 128, cbnb + i * 128,
            cbnm + i * 128, cbnv + i * 128, h_bf, (i < 2) ? 1 : 0);
    }
    k_edgemlp<<<N_EDGES / 64, 256, 0, stream>>>(
        h_bf, ei, d_in[2], flag, w1t, w2t,
        cem1b, cemlg, cemlb, cem2b, cem3w, cem3b, out);
}

// Round 6
// 594.690 us; speedup vs baseline: 2.9749x; 1.0787x over previous
//
#include <hip/hip_runtime.h>
#include <hip/hip_bf16.h>

// ShockPropagationGNN — round 5.
// - aggregate: single-pass softmax (no max shift; logits O(1), fp32-safe).
// - gemm/edgemlp epilogues: col = w*32 + 2*l15 + nt -> packed u32 stores
//   (ds_write_b32 for za, global u32 for C).
// - edgemlp LDS 40960B (part aliases sums) -> 4 blocks/CU.

#define N_NODES 50000
#define N_EDGES 200000
#define ETOT    (N_EDGES + N_NODES)
#define HID     128
#define LN_EPS  1e-5f
#define NEG     0.2f

typedef __hip_bfloat16 bf16;
typedef __attribute__((ext_vector_type(8))) short v8s;
typedef __attribute__((ext_vector_type(4))) float v4f;
#define MFMA(a, b, c) __builtin_amdgcn_mfma_f32_16x16x32_bf16(a, b, c, 0, 0, 0)

__device__ __forceinline__ float b2f(unsigned short s) {
    return __uint_as_float(((unsigned int)s) << 16);
}
__device__ __forceinline__ unsigned short f2b(float f) {
    __hip_bfloat16 h = __float2bfloat16(f);
    return *reinterpret_cast<unsigned short*>(&h);
}
__device__ __forceinline__ unsigned int pack2(float a, float b) {
    return (unsigned int)f2b(a) | ((unsigned int)f2b(b) << 16);
}
__device__ __forceinline__ float pread(const void* p, size_t i, int isbf) {
    if (isbf) return b2f(((const unsigned short*)p)[i]);
    return ((const float*)p)[i];
}

__global__ void k_fill(float* out, int n, float v) {
    int i = blockIdx.x * blockDim.x + threadIdx.x;
    if (i < n) out[i] = v;
}

// ------------------------------------------------------------ dtype detect
__global__ void k_detect(const unsigned short* __restrict__ xbuf,
                         int* __restrict__ flag) {
    int sane = 0;
    for (int j = threadIdx.x; j < 4096; j += 64) {
        unsigned short v = xbuf[2 * j];
        int e = (v >> 7) & 0xFF;
        if (v == 0 || (e > 96 && e < 160)) sane++;
    }
    for (int off = 32; off > 0; off >>= 1) sane += __shfl_down(sane, off);
    if (threadIdx.x == 0) flag[0] = (sane * 10 >= 4096 * 9) ? 1 : 0;
}

// ------------------------------------------------------------ prep (fused)
struct PrepArgs {
    const void *encw, *encb, *enlg, *enlb, *gatw, *asrc, *adst, *bias,
               *bng, *bnb, *bnm, *bnv, *em1w, *em1b, *emlg, *emlb,
               *em2w, *em2b, *em3w, *em3b;
};
#define PREP_ITEMS (150000 + 8193 + 196608 + 36864 + 8192)
__global__ void k_prep(PrepArgs a, float* __restrict__ pool,
                       unsigned short* __restrict__ gwt,
                       unsigned short* __restrict__ w1t,
                       unsigned short* __restrict__ w2t,
                       float* __restrict__ down, int* __restrict__ deg,
                       int* __restrict__ fill, const int* __restrict__ flag) {
    int i = blockIdx.x * 256 + threadIdx.x;
    int bf = flag[0];
    if (i < 150000) {
        int which = i / 50000, idx = i - which * 50000;
        if (which == 0) down[idx] = 0.f;
        else if (which == 1) deg[idx] = 0;
        else fill[idx] = 0;
        return;
    }
    i -= 150000;
    if (i < 8193) {
        const void* s; int off;
        if      (i < 2304) { s = a.encw; off = 0;    }
        else if (i < 2432) { s = a.encb; off = 2304; }
        else if (i < 2560) { s = a.enlg; off = 2432; }
        else if (i < 2688) { s = a.enlb; off = 2560; }
        else if (i < 4224) { s = a.asrc; off = 2688; }
        else if (i < 5760) { s = a.adst; off = 4224; }
        else if (i < 6144) { s = a.bias; off = 5760; }
        else if (i < 6528) { s = a.bng;  off = 6144; }
        else if (i < 6912) { s = a.bnb;  off = 6528; }
        else if (i < 7296) { s = a.bnm;  off = 6912; }
        else if (i < 7680) { s = a.bnv;  off = 7296; }
        else if (i < 7808) { s = a.em1b; off = 7680; }
        else if (i < 7936) { s = a.emlg; off = 7808; }
        else if (i < 8064) { s = a.emlb; off = 7936; }
        else if (i < 8128) { s = a.em2b; off = 8064; }
        else if (i < 8192) { s = a.em3w; off = 8128; }
        else               { s = a.em3b; off = 8192; }
        pool[i] = pread(s, i - off, bf);
        return;
    }
    i -= 8193;
    if (i < 196608) {   // gwt[L][n=512][k=128] = gat_w[L][k][n]
        int L = i >> 16, rem = i & 65535, n = rem >> 7, k = rem & 127;
        gwt[i] = f2b(pread(a.gatw, (size_t)L * 65536 + (size_t)k * 512 + n, bf));
        return;
    }
    i -= 196608;
    if (i < 36864) {    // w1t[n=128][k=288] = em1_w[k][n], zero-pad k>=264
        int n = i / 288, k = i - n * 288;
        w1t[i] = (k < 264) ? f2b(pread(a.em1w, (size_t)k * 128 + n, bf)) : 0;
        return;
    }
    i -= 36864;
    if (i < 8192) {     // w2t[n=64][k=128] = em2_w[k][n]
        int n = i >> 7, k = i & 127;
        w2t[i] = f2b(pread(a.em2w, (size_t)k * 64 + n, bf));
    }
}

// ------------------------------------------------------------ graph build
__global__ void k_graph(const int* __restrict__ ei, const int* __restrict__ shock,
                        float* __restrict__ down, int* __restrict__ deg) {
    int e = blockIdx.x * blockDim.x + threadIdx.x;
    if (e < ETOT) {
        int d = (e < N_EDGES) ? ei[N_EDGES + e] : (e - N_EDGES);
        atomicAdd(&deg[d], 1);
        if (e < N_EDGES && shock[ei[e]] != 0) down[d] = 1.f;
    }
}

__global__ __launch_bounds__(1024) void k_scan(
        const int* __restrict__ deg, int* __restrict__ row_start) {
    __shared__ int wsum[16];
    __shared__ int wexcl[16];
    const int PER = 49;
    int t = threadIdx.x, lane = t & 63, wid = t >> 6;
    int base = t * PER;
    int tot = 0;
    for (int i = 0; i < PER; i++) {
        int idx = base + i;
        if (idx < N_NODES) tot += deg[idx];
    }
    int inc = tot;
#pragma unroll
    for (int off = 1; off < 64; off <<= 1) {
        int v = __shfl_up(inc, off);
        if (lane >= off) inc += v;
    }
    if (lane == 63) wsum[wid] = inc;
    __syncthreads();
    if (wid == 0) {
        int wv = (lane < 16) ? wsum[lane] : 0;
        int winc = wv;
#pragma unroll
        for (int off = 1; off < 16; off <<= 1) {
            int v = __shfl_up(winc, off);
            if (lane >= off) winc += v;
        }
        if (lane < 16) wexcl[lane] = winc - wv;
    }
    __syncthreads();
    int run = wexcl[wid] + (inc - tot);
    for (int i = 0; i < PER; i++) {
        int idx = base + i;
        if (idx < N_NODES) {
            row_start[idx] = run;
            run += deg[idx];
        }
    }
    if (t == 0) row_start[N_NODES] = ETOT;
}

__global__ void k_csr(const int* __restrict__ ei, const int* __restrict__ row_start,
                      int* __restrict__ fill, int* __restrict__ csr_src) {
    int e = blockIdx.x * blockDim.x + threadIdx.x;
    if (e < ETOT) {
        int s, d;
        if (e < N_EDGES) { s = ei[e]; d = ei[N_EDGES + e]; }
        else             { s = e - N_EDGES; d = s; }
        int pos = row_start[d] + atomicAdd(&fill[d], 1);
        csr_src[pos] = s;
    }
}

// ------------------------------------------------------------ encoder -> h bf16
__global__ __launch_bounds__(128) void k_encoder(
        const void* __restrict__ xraw, const int* __restrict__ flag,
        const int* __restrict__ shock, const float* __restrict__ down,
        const float* __restrict__ enc_w, const float* __restrict__ enc_b,
        const float* __restrict__ ln_g, const float* __restrict__ ln_b,
        unsigned short* __restrict__ h) {
    int n = blockIdx.x, c = threadIdx.x;
    __shared__ float xa[18];
    __shared__ float red[4];
    int bf = flag[0];
    if (c < 16)       xa[c]  = pread(xraw, (size_t)n * 16 + c, bf);
    else if (c == 16) xa[16] = (float)shock[n];
    else if (c == 17) xa[17] = down[n];
    __syncthreads();
    float acc = enc_b[c];
#pragma unroll
    for (int k = 0; k < 18; k++) acc = fmaf(xa[k], enc_w[k * HID + c], acc);
    float s = acc, q = acc * acc;
    for (int off = 32; off > 0; off >>= 1) {
        s += __shfl_down(s, off);
        q += __shfl_down(q, off);
    }
    if ((c & 63) == 0) { red[(c >> 6) * 2] = s; red[(c >> 6) * 2 + 1] = q; }
    __syncthreads();
    float S = red[0] + red[2], Q = red[1] + red[3];
    float mu = S * (1.f / 128.f);
    float var = Q * (1.f / 128.f) - mu * mu;
    float rstd = rsqrtf(var + LN_EPS);
    float v = (acc - mu) * rstd * ln_g[c] + ln_b[c];
    h[(size_t)n * HID + c] = f2b(fmaxf(v, 0.f));
}

// ------------------------------------------------------------ GAT GEMM + logits
// Thread cols: col(nt) = n0 + w*32 + 2*l15 + nt (adjacent pair -> u32 stores).
__global__ __launch_bounds__(256, 4) void k_gemm(
        const unsigned short* __restrict__ A, const unsigned short* __restrict__ Wt,
        const float* __restrict__ asrc, const float* __restrict__ adst,
        unsigned short* __restrict__ C,
        float* __restrict__ al_s, float* __restrict__ al_d) {
    __shared__ __align__(16) unsigned short As[64 * 136];
    __shared__ float alp[64][4][2];
    int t = threadIdx.x;
    int lane = t & 63, w = t >> 6, l15 = lane & 15, q = lane >> 4;
    int m0 = blockIdx.x * 64, n0 = blockIdx.y * 128, head = blockIdx.y;
    int c0 = n0 + w * 32 + 2 * l15, c1 = c0 + 1;

    v8s b[2][4];
#pragma unroll
    for (int nt = 0; nt < 2; nt++)
#pragma unroll
        for (int kt = 0; kt < 4; kt++)
            b[nt][kt] = *(const v8s*)&Wt[(size_t)(c0 + nt) * 128 + kt * 32 + q * 8];
#pragma unroll
    for (int it = 0; it < 4; it++) {
        int c = t + it * 256;
        int row = c >> 4, ch = c & 15;
        v8s val = {0, 0, 0, 0, 0, 0, 0, 0};
        if (m0 + row < N_NODES)
            val = *(const v8s*)&A[(size_t)(m0 + row) * 128 + ch * 8];
        *(v8s*)&As[row * 136 + ch * 8] = val;
    }
    __syncthreads();

    v4f acc[4][2] = {};
#pragma unroll
    for (int kt = 0; kt < 4; kt++)
#pragma unroll
        for (int mt = 0; mt < 4; mt++) {
            v8s a = *(const v8s*)&As[(mt * 16 + l15) * 136 + kt * 32 + q * 8];
            acc[mt][0] = MFMA(a, b[0][kt], acc[mt][0]);
            acc[mt][1] = MFMA(a, b[1][kt], acc[mt][1]);
        }
    // packed C store: two adjacent bf16 cols per u32
#pragma unroll
    for (int mt = 0; mt < 4; mt++)
#pragma unroll
        for (int r = 0; r < 4; r++) {
            int node = m0 + mt * 16 + q * 4 + r;
            if (node < N_NODES)
                *(unsigned int*)&C[(size_t)node * 512 + c0] =
                    pack2(acc[mt][0][r], acc[mt][1][r]);
        }

    // fused logits
    float ps0 = asrc[c0], ps1 = asrc[c1];
    float pd0 = adst[c0], pd1 = adst[c1];
#pragma unroll
    for (int mt = 0; mt < 4; mt++)
#pragma unroll
        for (int r = 0; r < 4; r++) {
            float vs = acc[mt][0][r] * ps0 + acc[mt][1][r] * ps1;
            float vd = acc[mt][0][r] * pd0 + acc[mt][1][r] * pd1;
#pragma unroll
            for (int off = 1; off < 16; off <<= 1) {
                vs += __shfl_xor(vs, off);
                vd += __shfl_xor(vd, off);
            }
            if (l15 == 0) {
                alp[mt * 16 + q * 4 + r][w][0] = vs;
                alp[mt * 16 + q * 4 + r][w][1] = vd;
            }
        }
    __syncthreads();
    if (t < 64) {
        int node = m0 + t;
        if (node < N_NODES) {
            float ss = alp[t][0][0] + alp[t][1][0] + alp[t][2][0] + alp[t][3][0];
            float sd = alp[t][0][1] + alp[t][1][1] + alp[t][2][1] + alp[t][3][1];
            al_s[node * 4 + head] = ss;
            al_d[node * 4 + head] = sd;
        }
    }
}

// ------------------------------------------------------------ aggregation
// One wave per node. SINGLE pass: softmax without max shift (logits O(1)).
__global__ __launch_bounds__(256) void k_aggregate(
        const unsigned short* __restrict__ xh, const float* __restrict__ al_src,
        const float* __restrict__ al_dst,
        const int* __restrict__ row_start, const int* __restrict__ csr_src,
        const float* __restrict__ bias,
        const float* __restrict__ bn_g, const float* __restrict__ bn_b,
        const float* __restrict__ bn_m, const float* __restrict__ bn_v,
        unsigned short* __restrict__ h, int relu_flag) {
    int w = threadIdx.x >> 6, l = threadIdx.x & 63;
    int n = blockIdx.x * 4 + w;
    int hh = l >> 4, c8 = l & 15;
    int r0 = row_start[n], r1 = row_start[n + 1];
    float ad = al_dst[n * 4 + hh];
    float sh = 0.f;
    float acc[8] = {};
    for (int j = r0; j < r1; j++) {
        int s = csr_src[j];
        float a = al_src[s * 4 + hh] + ad;
        a = (a >= 0.f) ? a : NEG * a;
        float we = __expf(a);
        sh += we;
        v8s row = *(const v8s*)&xh[(size_t)s * 512 + l * 8];
#pragma unroll
        for (int i = 0; i < 8; i++)
            acc[i] = fmaf(we, b2f((unsigned short)row[i]), acc[i]);
    }
    float inv = 1.f / (sh + 1e-16f);
#pragma unroll
    for (int i = 0; i < 8; i++) {
        acc[i] *= inv;
        acc[i] += __shfl_xor(acc[i], 16);
        acc[i] += __shfl_xor(acc[i], 32);
    }
    if (hh == 0) {
        int cbase = c8 * 8;
        short o[8];
#pragma unroll
        for (int i = 0; i < 8; i++) {
            int c = cbase + i;
            float v = 0.25f * acc[i] + bias[c];
            v = (v - bn_m[c]) * rsqrtf(bn_v[c] + LN_EPS) * bn_g[c] + bn_b[c];
            if (relu_flag) v = fmaxf(v, 0.f);
            o[i] = (short)f2b(v);
        }
        *(v8s*)&h[(size_t)n * 128 + cbase] = *(const v8s*)o;
    }
}

// ------------------------------------------------------------ edge MLP (MFMA)
// Thread cols: c0 = w*32 + 2*l15, c1 = c0+1 -> packed ds_write_b32 za stores.
// LDS = 37888(in_s) + 2048(sums; part aliases) + 512(stats) + 512(idx) = 40960
__global__ __launch_bounds__(256, 4) void k_edgemlp(
        const unsigned short* __restrict__ h, const int* __restrict__ ei,
        const void* __restrict__ eraw, const int* __restrict__ flag,
        const unsigned short* __restrict__ w1t, const unsigned short* __restrict__ w2t,
        const float* __restrict__ em1b, const float* __restrict__ lng,
        const float* __restrict__ lnb, const float* __restrict__ em2b,
        const float* __restrict__ em3w, const float* __restrict__ em3b,
        float* __restrict__ out) {
    __shared__ __align__(16) unsigned short in_s[64 * 296]; // za aliases
    __shared__ float sums[64][4][2];   // part[4][64] aliases this after stats
    __shared__ float stats[64][2];
    __shared__ int   idx_s[128];
    unsigned short* za = in_s;
    float* part = &sums[0][0][0];      // [w*64 + i]

    int t = threadIdx.x;
    int lane = t & 63, w = t >> 6, l15 = lane & 15, q = lane >> 4;
    int e0 = blockIdx.x * 64;
    int bf = flag[0];
    int c0 = w * 32 + 2 * l15, c1 = c0 + 1;

    v8s b1[2][9];
#pragma unroll
    for (int nt = 0; nt < 2; nt++)
#pragma unroll
        for (int kt = 0; kt < 9; kt++)
            b1[nt][kt] = *(const v8s*)&w1t[(size_t)(c0 + nt) * 288 + kt * 32 + q * 8];
    v8s b2[4];
#pragma unroll
    for (int kt = 0; kt < 4; kt++)
        b2[kt] = *(const v8s*)&w2t[(size_t)(w * 16 + l15) * 128 + kt * 32 + q * 8];

    float bc0 = em1b[c0], bc1 = em1b[c1];
    float lg0 = lng[c0], lg1 = lng[c1], lb0 = lnb[c0], lb1 = lnb[c1];

    if (t < 64) {
        idx_s[t * 2]     = ei[e0 + t];
        idx_s[t * 2 + 1] = ei[N_EDGES + e0 + t];
    }
    __syncthreads();

    for (int idx = t; idx < 64 * 36; idx += 256) {
        int row = idx / 36, c = idx - row * 36;
        v8s val = {0, 0, 0, 0, 0, 0, 0, 0};
        if (c < 32) {
            int node = idx_s[row * 2 + (c >> 4)];
            val = *(const v8s*)&h[(size_t)node * 128 + (c & 15) * 8];
        } else if (c == 32) {
            size_t eb = (size_t)(e0 + row) * 8;
            if (bf) {
                val = *(const v8s*)((const unsigned short*)eraw + eb);
            } else {
                short tmp[8];
#pragma unroll
                for (int j = 0; j < 8; j++)
                    tmp[j] = (short)f2b(((const float*)eraw)[eb + j]);
                val = *(const v8s*)tmp;
            }
        }
        *(v8s*)&in_s[row * 296 + c * 8] = val;
    }
    __syncthreads();

    v4f acc1[4][2] = {};
#pragma unroll
    for (int kt = 0; kt < 9; kt++)
#pragma unroll
        for (int mt = 0; mt < 4; mt++) {
            v8s a = *(const v8s*)&in_s[(mt * 16 + l15) * 296 + kt * 32 + q * 8];
            acc1[mt][0] = MFMA(a, b1[0][kt], acc1[mt][0]);
            acc1[mt][1] = MFMA(a, b1[1][kt], acc1[mt][1]);
        }

    // LN stats from registers
#pragma unroll
    for (int mt = 0; mt < 4; mt++)
#pragma unroll
        for (int r = 0; r < 4; r++) {
            float v0 = acc1[mt][0][r] + bc0;
            float v1 = acc1[mt][1][r] + bc1;
            float s = v0 + v1;
            float qq = v0 * v0 + v1 * v1;
#pragma unroll
            for (int off = 1; off < 16; off <<= 1) {
                s  += __shfl_xor(s, off);
                qq += __shfl_xor(qq, off);
            }
            if (l15 == 0) {
                sums[mt * 16 + q * 4 + r][w][0] = s;
                sums[mt * 16 + q * 4 + r][w][1] = qq;
            }
        }
    __syncthreads();
    if (t < 64) {
        float S = sums[t][0][0] + sums[t][1][0] + sums[t][2][0] + sums[t][3][0];
        float Q = sums[t][0][1] + sums[t][1][1] + sums[t][2][1] + sums[t][3][1];
        float mu = S * (1.f / 128.f);
        float var = Q * (1.f / 128.f) - mu * mu;
        stats[t][0] = mu;
        stats[t][1] = rsqrtf(var + LN_EPS);
    }
    __syncthreads();

    // normalize + relu -> za (packed b32 writes, 2 adjacent cols)
#pragma unroll
    for (int mt = 0; mt < 4; mt++)
#pragma unroll
        for (int r = 0; r < 4; r++) {
            int row = mt * 16 + q * 4 + r;
            float mu = stats[row][0], rstd = stats[row][1];
            float z0 = (acc1[mt][0][r] + bc0 - mu) * rstd * lg0 + lb0;
            float z1 = (acc1[mt][1][r] + bc1 - mu) * rstd * lg1 + lb1;
            *(unsigned int*)&za[row * 136 + c0] =
                pack2(fmaxf(z0, 0.f), fmaxf(z1, 0.f));
        }
    __syncthreads();

    v4f acc2[4] = {};
#pragma unroll
    for (int kt = 0; kt < 4; kt++)
#pragma unroll
        for (int mt = 0; mt < 4; mt++) {
            v8s a = *(const v8s*)&za[(mt * 16 + l15) * 136 + kt * 32 + q * 8];
            acc2[mt] = MFMA(a, b2[kt], acc2[mt]);
        }
    __syncthreads();   // za/sums reads done; part may overwrite sums

    {
        int col = w * 16 + l15;
        float b2c = em2b[col], w3c = em3w[col];
#pragma unroll
        for (int mt = 0; mt < 4; mt++)
#pragma unroll
            for (int r = 0; r < 4; r++) {
                float v = fmaxf(acc2[mt][r] + b2c, 0.f) * w3c;
#pragma unroll
                for (int off = 1; off < 16; off <<= 1) v += __shfl_xor(v, off);
                if (l15 == 0) part[w * 64 + mt * 16 + q * 4 + r] = v;
            }
    }
    __syncthreads();
    if (t < 64)
        out[e0 + t] = part[t] + part[64 + t] + part[128 + t] + part[192 + t]
                    + em3b[0];
}

// ------------------------------------------------------------ launch
extern "C" __attribute__((visibility("default")))
void kernel_launch(void* const* d_in, const int* in_sizes, int n_in,
                   void* d_out, int out_size, void* d_ws, size_t ws_size,
                   hipStream_t stream) {
    float* out = (float*)d_out;

    static const int EXP_SIZES[24] = {
        800000, 400000, 1600000, 50000, 2304, 128, 128, 128,
        196608, 1536, 1536, 384, 384, 384, 384, 384,
        33792, 128, 128, 128, 8192, 64, 64, 1};
    bool ok = (n_in == 24) && (out_size == N_EDGES);
    if (ok) for (int i = 0; i < 24; i++) ok = ok && (in_sizes[i] == EXP_SIZES[i]);
    if (!ok) {
        k_fill<<<(out_size + 255) / 256, 256, 0, stream>>>(out, out_size, 4.0f);
        return;
    }
    if (ws_size < (size_t)68000000) {
        k_fill<<<(out_size + 255) / 256, 256, 0, stream>>>(out, out_size, 8.0f);
        return;
    }

    const int* ei    = (const int*)d_in[1];
    const int* shock = (const int*)d_in[3];

    char* ws = (char*)d_ws;
    unsigned short* h_bf  = (unsigned short*)(ws + 0);          // 12,800,000
    unsigned short* xh    = (unsigned short*)(ws + 12800000);   // 51,200,000
    float* al_s    = (float*)(ws + 64000000);
    float* al_d    = (float*)(ws + 64800000);
    float* down    = (float*)(ws + 65600000);
    int*   deg     = (int*)  (ws + 65800000);
    int*   row_st  = (int*)  (ws + 66000000);
    int*   fill    = (int*)  (ws + 66200064);
    int*   csr_src = (int*)  (ws + 66400064);
    int*   flag    = (int*)  (ws + 67400064);
    unsigned short* gwt = (unsigned short*)(ws + 67400128);
    unsigned short* w1t = (unsigned short*)(ws + 67793344);
    unsigned short* w2t = (unsigned short*)(ws + 67867072);
    float* pool    = (float*)(ws + 67883456);

    float* cencw = pool + 0;    float* cencb = pool + 2304;
    float* cenlg = pool + 2432; float* cenlb = pool + 2560;
    float* casrc = pool + 2688; float* cadst = pool + 4224;
    float* cbias = pool + 5760; float* cbng  = pool + 6144;
    float* cbnb  = pool + 6528; float* cbnm  = pool + 6912;
    float* cbnv  = pool + 7296; float* cem1b = pool + 7680;
    float* cemlg = pool + 7808; float* cemlb = pool + 7936;
    float* cem2b = pool + 8064; float* cem3w = pool + 8128;
    float* cem3b = pool + 8192;

    k_detect<<<1, 64, 0, stream>>>((const unsigned short*)d_in[0], flag);

    PrepArgs pa;
    pa.encw = d_in[4];  pa.encb = d_in[5];  pa.enlg = d_in[6];  pa.enlb = d_in[7];
    pa.gatw = d_in[8];  pa.asrc = d_in[9];  pa.adst = d_in[10]; pa.bias = d_in[11];
    pa.bng  = d_in[12]; pa.bnb  = d_in[13]; pa.bnm  = d_in[14]; pa.bnv  = d_in[15];
    pa.em1w = d_in[16]; pa.em1b = d_in[17]; pa.emlg = d_in[18]; pa.emlb = d_in[19];
    pa.em2w = d_in[20]; pa.em2b = d_in[21]; pa.em3w = d_in[22]; pa.em3b = d_in[23];
    k_prep<<<(PREP_ITEMS + 255) / 256, 256, 0, stream>>>(
        pa, pool, gwt, w1t, w2t, down, deg, fill, flag);

    k_graph<<<(ETOT + 255) / 256, 256, 0, stream>>>(ei, shock, down, deg);
    k_scan<<<1, 1024, 0, stream>>>(deg, row_st);
    k_csr<<<(ETOT + 255) / 256, 256, 0, stream>>>(ei, row_st, fill, csr_src);
    k_encoder<<<N_NODES, 128, 0, stream>>>(d_in[0], flag, shock, down,
                                           cencw, cencb, cenlg, cenlb, h_bf);
    for (int i = 0; i < 3; i++) {
        k_gemm<<<dim3(782, 4), 256, 0, stream>>>(
            h_bf, gwt + (size_t)i * 65536, casrc + i * 512, cadst + i * 512,
            xh, al_s, al_d);
        k_aggregate<<<N_NODES / 4, 256, 0, stream>>>(
            xh, al_s, al_d, row_st, csr_src,
            cbias + i * 128, cbng + i * 128, cbnb + i * 128,
            cbnm + i * 128, cbnv + i * 128, h_bf, (i < 2) ? 1 : 0);
    }
    k_edgemlp<<<N_EDGES / 64, 256, 0, stream>>>(
        h_bf, ei, d_in[2], flag, w1t, w2t,
        cem1b, cemlg, cemlb, cem2b, cem3w, cem3b, out);
}